// Round 11
// baseline (550.786 us; speedup 1.0000x reference)
//
#include <hip/hip_runtime.h>
#include <math.h>

#define LEAK 0.01f

typedef __bf16 bf16x8 __attribute__((ext_vector_type(8)));
typedef float f32x4 __attribute__((ext_vector_type(4)));
typedef unsigned short ushort;
typedef unsigned int uint32;

struct HL { ushort h, l; };

// split fp32 into bf16 hi + bf16 lo (both RNE): x ~= hi + lo, err ~2^-17 rel
__device__ inline HL split_bf16(float x) {
    unsigned u = __float_as_uint(x);
    unsigned hr = (u + 0x7FFFu + ((u >> 16) & 1u)) >> 16;
    float fh = __uint_as_float(hr << 16);
    float r = x - fh;
    unsigned v = __float_as_uint(r);
    unsigned lr = (v + 0x7FFFu + ((v >> 16) & 1u)) >> 16;
    HL out; out.h = (ushort)hr; out.l = (ushort)lr;
    return out;
}

// ================= staged-B raw load: 64n x 64k fp32 tile, 16 floats/thread =================
template<int MODE>
__device__ inline void stage_load(float (&pv)[4][4], const float* __restrict__ Bf,
                                  int kbase, int n0, int tid,
                                  int Ci, int Hin, int Ho, int lgHo, int lgHW) {
#pragma unroll
    for (int r = 0; r < 4; ++r) {
        int g = r * 256 + tid;          // 0..1023
        int nl = g >> 4, kgrp = g & 15;
        int n = n0 + nl;
        if (MODE == 0) {
            int k4 = kbase + (kgrp << 2);
            int ic = k4 >> 4, kh = (k4 >> 2) & 3;
            int ow = n & (Ho - 1), oh = (n >> lgHo) & (Ho - 1), b = n >> (lgHo + lgHo);
            int ih = oh * 2 - 1 + kh;
            int ihc = ih < 0 ? 0 : (ih >= Hin ? Hin - 1 : ih);
            int iwb = ow * 2 - 1;
            size_t base = ((size_t)(b * Ci + ic) * Hin + ihc) * Hin;
#pragma unroll
            for (int e = 0; e < 4; ++e) {
                int iw = iwb + e;
                int iwc = iw < 0 ? 0 : (iw >= Hin ? Hin - 1 : iw);
                pv[r][e] = Bf[base + iwc];
            }
        } else {
            int c = kbase + (kgrp << 2);
            int b = n >> lgHW, hw = n & ((1 << lgHW) - 1);
            size_t base = (((size_t)(b * Ci + c)) << lgHW) + hw;
            size_t str = (size_t)1 << lgHW;
#pragma unroll
            for (int e = 0; e < 4; ++e) pv[r][e] = Bf[base + e * str];
        }
    }
}

// ================= bf16-split MFMA GEMM, fused BN+leaky on B, 64-k stages =================
// Block tile 128M x 64N, 4 waves of 32M x 64N. LDS stage = 64 k (2 MFMA sub-steps).
// A: fragment-ordered bf16 hi/lo (verified r9).  B: raw fp32; BN->leaky->mask->split->pack
// applied at LDS-write (verified r10).  C = Ah*Bh + Ah*Bl + Al*Bh (verified r7-r10).
// Optional fused output BN-stats (statsOut) for KS==1 MODE 1 layers.
template<int MODE>
__global__ __launch_bounds__(256, 3) void gemm_mfma(
    const ushort* __restrict__ Ah, const ushort* __restrict__ Al,
    const float* __restrict__ Bf,
    const float* __restrict__ bnt, const float* __restrict__ gamma,
    const float* __restrict__ beta, float invN, int chanShift,
    const float* __restrict__ bias, float* __restrict__ P,
    float* __restrict__ statsOut,
    int Mtiles, int Ntiles, int K, int Kslice, int KS, int outSize,
    int Ci, int Hin, int Co, int Ho, int lgHo,
    int lgHW, int lgHin, int lgCo, int lgk)
{
    __shared__ __align__(16) uint32 Bsp[64 * 68];   // [n][k] packed, stride 68
    __shared__ float scs[256], shs[256];
    __shared__ float st1[32], st2[32];

    int bid = blockIdx.x;
    int ntile = bid % Ntiles; bid /= Ntiles;
    int mtile = bid % Mtiles;
    int ks = bid / Mtiles;
    int tid = threadIdx.x;
    int lane = tid & 63, w = tid >> 6;
    int quad = lane >> 4, tl = lane & 15;
    int n0 = ntile << 6, m0 = mtile << 7, k0 = ks * Kslice;
    int Kt = K >> 5;

    bool useBN = (bnt != nullptr);
    int c0 = k0 >> chanShift;
    if (useBN) {
        int nch = Kslice >> chanShift;
        for (int c = tid; c < nch; c += 256) {
            float m = bnt[(c0 + c) * 2] * invN;
            float var = bnt[(c0 + c) * 2 + 1] * invN - m * m;
            float scale = gamma[c0 + c] * rsqrtf(var + 1e-5f);
            scs[c] = scale;
            shs[c] = beta[c0 + c] - m * scale;
        }
    }
    if (MODE == 1 && statsOut && tid < 32) { st1[tid] = 0.f; st2[tid] = 0.f; }
    __syncthreads();

    f32x4 zero4 = {0.f, 0.f, 0.f, 0.f};
    f32x4 acc[2][4];
#pragma unroll
    for (int mt = 0; mt < 2; ++mt)
#pragma unroll
        for (int nt = 0; nt < 4; ++nt) acc[mt][nt] = zero4;

    float pv[4][4];
    stage_load<MODE>(pv, Bf, k0, n0, tid, Ci, Hin, Ho, lgHo, lgHW);

    for (int kc = 0; kc < Kslice; kc += 64) {
        int kbase = k0 + kc;
        // ---- transform + regs -> LDS (64n x 64k) ----
#pragma unroll
        for (int r = 0; r < 4; ++r) {
            int g = r * 256 + tid;
            int nl = g >> 4, kgrp = g & 15;
            int k4 = kbase + (kgrp << 2);
            uint32 pk[4];
            if (MODE == 0) {
                int ic = k4 >> 4, kh = (k4 >> 2) & 3;
                int n = n0 + nl;
                int ow = n & (Ho - 1), oh = (n >> lgHo) & (Ho - 1);
                int ih = oh * 2 - 1 + kh;
                bool rowok = (unsigned)ih < (unsigned)Hin;
                int iwb = ow * 2 - 1;
                float sc_ = useBN ? scs[ic - c0] : 0.f;
                float sh_ = useBN ? shs[ic - c0] : 0.f;
#pragma unroll
                for (int e = 0; e < 4; ++e) {
                    int iw = iwb + e;
                    bool ok = rowok && ((unsigned)iw < (unsigned)Hin);
                    float f = pv[r][e];
                    if (useBN) { f = f * sc_ + sh_; f = f >= 0.f ? f : LEAK * f; }
                    if (!ok) f = 0.f;
                    HL s = split_bf16(f);
                    pk[e] = ((uint32)s.h << 16) | s.l;
                }
            } else {
#pragma unroll
                for (int e = 0; e < 4; ++e) {
                    float f = pv[r][e];
                    if (useBN) {
                        int lc = k4 + e - k0;
                        f = f * scs[lc] + shs[lc];
                        f = f >= 0.f ? f : LEAK * f;
                    }
                    HL s = split_bf16(f);
                    pk[e] = ((uint32)s.h << 16) | s.l;
                }
            }
            *(uint4*)&Bsp[nl * 68 + (kgrp << 2)] = make_uint4(pk[0], pk[1], pk[2], pk[3]);
        }
        __syncthreads();

        // ---- prefetch next 64-k B tile (raw -> loads in flight through 2 MFMA subs) ----
        bool more = (kc + 64) < Kslice;
        float pvn[4][4];
        if (more) stage_load<MODE>(pvn, Bf, kbase + 64, n0, tid, Ci, Hin, Ho, lgHo, lgHW);

        // ---- two 32-k MFMA sub-steps ----
#pragma unroll
        for (int s = 0; s < 2; ++s) {
            int kt = (kbase >> 5) + s;
            bf16x8 afh[2], afl[2];
#pragma unroll
            for (int mt = 0; mt < 2; ++mt) {
                int mtAbs = (m0 >> 4) + (w << 1) + mt;
                size_t abase = (((size_t)mtAbs * Kt + kt) << 6) + lane;
                afh[mt] = *(const bf16x8*)(Ah + abase * 8);
                afl[mt] = *(const bf16x8*)(Al + abase * 8);
            }
            bf16x8 bfh[4], bfl[4];
#pragma unroll
            for (int nt = 0; nt < 4; ++nt) {
                int base = ((nt << 4) + tl) * 68 + (s << 5) + (quad << 3);
                uint4 ua = *(const uint4*)&Bsp[base];
                uint4 ub = *(const uint4*)&Bsp[base + 4];
                union { uint32 u[4]; bf16x8 v; } H, L;
                H.u[0] = __builtin_amdgcn_perm(ua.y, ua.x, 0x07060302u);
                H.u[1] = __builtin_amdgcn_perm(ua.w, ua.z, 0x07060302u);
                H.u[2] = __builtin_amdgcn_perm(ub.y, ub.x, 0x07060302u);
                H.u[3] = __builtin_amdgcn_perm(ub.w, ub.z, 0x07060302u);
                L.u[0] = __builtin_amdgcn_perm(ua.y, ua.x, 0x05040100u);
                L.u[1] = __builtin_amdgcn_perm(ua.w, ua.z, 0x05040100u);
                L.u[2] = __builtin_amdgcn_perm(ub.y, ub.x, 0x05040100u);
                L.u[3] = __builtin_amdgcn_perm(ub.w, ub.z, 0x05040100u);
                bfh[nt] = H.v; bfl[nt] = L.v;
            }
#pragma unroll
            for (int mt = 0; mt < 2; ++mt)
#pragma unroll
                for (int nt = 0; nt < 4; ++nt) {
                    acc[mt][nt] = __builtin_amdgcn_mfma_f32_16x16x32_bf16(afh[mt], bfh[nt], acc[mt][nt], 0, 0, 0);
                    acc[mt][nt] = __builtin_amdgcn_mfma_f32_16x16x32_bf16(afh[mt], bfl[nt], acc[mt][nt], 0, 0, 0);
                    acc[mt][nt] = __builtin_amdgcn_mfma_f32_16x16x32_bf16(afl[mt], bfh[nt], acc[mt][nt], 0, 0, 0);
                }
        }
        __syncthreads();
        if (more) {
#pragma unroll
            for (int r = 0; r < 4; ++r)
#pragma unroll
                for (int e = 0; e < 4; ++e) pv[r][e] = pvn[r][e];
        }
    }

    // ---- epilogue: D[m = quad*4+reg][n = tl] (verified r7-r10) ----
    float* dst = P + (size_t)ks * outSize;
    if (MODE == 0) {
#pragma unroll
        for (int nt = 0; nt < 4; ++nt) {
            int n = n0 + (nt << 4) + tl;
            int ow = n & (Ho - 1), oh = (n >> lgHo) & (Ho - 1), b = n >> (lgHo + lgHo);
#pragma unroll
            for (int mt = 0; mt < 2; ++mt) {
                int mb = m0 + (w << 5) + (mt << 4) + (quad << 2);
#pragma unroll
                for (int r = 0; r < 4; ++r) {
                    int oc = mb + r;
                    float v = acc[mt][nt][r];
                    if (KS == 1) v += bias[oc];
                    dst[((size_t)(b * Co + oc) * Ho + oh) * Ho + ow] = v;
                }
            }
        }
    } else {
        int kf = 1 << lgk;
        int Ho2 = Hin << lgk;
        float s1p[8], s2p[8];
#pragma unroll
        for (int i = 0; i < 8; ++i) { s1p[i] = 0.f; s2p[i] = 0.f; }
#pragma unroll
        for (int nt = 0; nt < 4; ++nt) {
            int n = n0 + (nt << 4) + tl;
            int b = n >> lgHW, hw = n & ((1 << lgHW) - 1);
            int h = hw >> lgHin, wp = hw & (Hin - 1);
#pragma unroll
            for (int mt = 0; mt < 2; ++mt) {
                int mb = m0 + (w << 5) + (mt << 4) + (quad << 2);
#pragma unroll
                for (int r = 0; r < 4; ++r) {
                    int m = mb + r;
                    int o = m & (Co - 1), ij = m >> lgCo;
                    int ii = ij >> lgk, jj = ij & (kf - 1);
                    float v = acc[mt][nt][r];
                    if (KS == 1) v += bias[o];
                    if (statsOut) { s1p[mt * 4 + r] += v; s2p[mt * 4 + r] += v * v; }
                    dst[((size_t)(b * Co + o) * Ho2 + (h << lgk) + ii) * Ho2 + (wp << lgk) + jj] = v;
                }
            }
        }
        if (statsOut) {
            // reduce over tl (16 lanes share channels) via shfl_xor on low 4 lane bits
#pragma unroll
            for (int i = 0; i < 8; ++i) {
#pragma unroll
                for (int msk = 1; msk < 16; msk <<= 1) {
                    s1p[i] += __shfl_xor(s1p[i], msk);
                    s2p[i] += __shfl_xor(s2p[i], msk);
                }
            }
            if (tl == 0) {
#pragma unroll
                for (int i = 0; i < 8; ++i) {
                    int o = ((w << 5) + ((i >> 2) << 4) + (quad << 2) + (i & 3)) & (Co - 1);
                    atomicAdd(&st1[o], s1p[i]);
                    atomicAdd(&st2[o], s2p[i]);
                }
            }
            __syncthreads();
            if (tid < 32) {
                atomicAdd(&statsOut[tid * 2],     st1[tid]);
                atomicAdd(&statsOut[tid * 2 + 1], st2[tid]);
            }
        }
    }
}

// ================= merged prologue: zero stats + codebook transpose + weight prep =================
__device__ inline int fragaddr(int m, int k, int K) {
    return ((((m >> 4) * (K >> 5) + (k >> 5)) << 9) | (((k >> 3) & 3) << 7) | ((m & 15) << 3) | (k & 7));
}

__global__ void prep_all(const float* __restrict__ w1, const float* __restrict__ w2,
                         const float* __restrict__ w3, const float* __restrict__ d0,
                         const float* __restrict__ d1, const float* __restrict__ d2,
                         ushort* __restrict__ WH, ushort* __restrict__ WL,
                         const float* __restrict__ cb, float* __restrict__ cbT,
                         float* __restrict__ bnt) {
    int idx = blockIdx.x * 256 + threadIdx.x;
    if (idx < 6144) bnt[idx] = 0.f;
    if (idx < 131072) {
        int k = idx & 511, c = idx >> 9;
        cbT[idx] = cb[k * 256 + c];
    }
    if (idx >= 2269184) return;
    float v; int dst;
    if (idx < 131072) {                      // enc1: M=128 K=1024
        int m = idx >> 10, k = idx & 1023;
        v = w1[idx];
        dst = fragaddr(m, k, 1024);
    } else if (idx < 655360) {               // enc2: M=256 K=2048
        int i = idx - 131072;
        int m = i >> 11, k = i & 2047;
        v = w2[i];
        dst = 131072 + fragaddr(m, k, 2048);
    } else if (idx < 1703936) {              // enc3: M=256 K=4096
        int i = idx - 655360;
        int m = i >> 12, k = i & 4095;
        v = w3[i];
        dst = 655360 + fragaddr(m, k, 4096);
    } else if (idx < 2228224) {              // dec0: M=2048 K=256
        int i = idx - 1703936;
        int m = i >> 8, c = i & 255;
        int o = m & 127, ij = m >> 7;
        v = d0[((size_t)c * 128 + o) * 16 + ij];
        dst = 1703936 + fragaddr(m, c, 256);
    } else if (idx < 2260992) {              // dec1: M=256 K=128
        int i = idx - 2228224;
        int m = i >> 7, c = i & 127;
        int o = m & 63, ij = m >> 6;
        v = d1[((size_t)c * 64 + o) * 4 + ij];
        dst = 2228224 + fragaddr(m, c, 128);
    } else {                                 // dec2: M=128 K=64
        int i = idx - 2260992;
        int m = i >> 6, c = i & 63;
        int o = m & 31, ij = m >> 5;
        v = d2[((size_t)c * 32 + o) * 4 + ij];
        dst = 2260992 + fragaddr(m, c, 64);
    }
    HL s = split_bf16(v);
    WH[dst] = s.h; WL[dst] = s.l;
}

// ================= enc0 direct conv (Ci=3) with fused BN stats =================
template<int OCT>
__global__ __launch_bounds__(256) void conv4x4(
    const float* __restrict__ x, const float* __restrict__ w,
    const float* __restrict__ bias, float* __restrict__ P,
    float* __restrict__ bnt,
    int B, int Ci, int Hin, int Co, int Ho)
{
    int ogn = Co / OCT;
    int ntile = (B * Ho * Ho) >> 8;
    int bid = blockIdx.x;
    int tile = bid % ntile; bid /= ntile;
    int og = bid % ogn;
    int oc0 = og * OCT;

    int px = (tile << 8) + threadIdx.x;
    int ow = px % Ho; int t = px / Ho;
    int oh = t % Ho;  int b = t / Ho;

    int off[16]; float fm[16];
    int ih0 = oh * 2 - 1, iw0 = ow * 2 - 1;
#pragma unroll
    for (int kh = 0; kh < 4; ++kh)
#pragma unroll
        for (int kw = 0; kw < 4; ++kw) {
            int ih = ih0 + kh, iw = iw0 + kw;
            bool ok = (ih >= 0) && (ih < Hin) && (iw >= 0) && (iw < Hin);
            int ihc = ih < 0 ? 0 : (ih >= Hin ? Hin - 1 : ih);
            int iwc = iw < 0 ? 0 : (iw >= Hin ? Hin - 1 : iw);
            off[kh * 4 + kw] = ihc * Hin + iwc;
            fm[kh * 4 + kw] = ok ? 1.f : 0.f;
        }

    float acc[OCT];
#pragma unroll
    for (int u = 0; u < OCT; ++u) acc[u] = bias[oc0 + u];

    const float* xc = x + (size_t)b * Ci * Hin * Hin;
    const float* wi = w + (size_t)oc0 * Ci * 16;
    int HinHin = Hin * Hin;
    for (int ic = 0; ic < Ci; ++ic) {
        float xv[16];
#pragma unroll
        for (int q = 0; q < 16; ++q) xv[q] = xc[off[q]] * fm[q];
#pragma unroll
        for (int u = 0; u < OCT; ++u) {
            const float* wo = wi + (size_t)u * Ci * 16;
            float a = acc[u];
#pragma unroll
            for (int q = 0; q < 16; ++q) a += xv[q] * wo[q];
            acc[u] = a;
        }
        xc += HinHin;
        wi += 16;
    }
    size_t obase = (((size_t)b * Co + oc0) * Ho + oh) * Ho + ow;
    size_t opl = (size_t)Ho * Ho;
#pragma unroll
    for (int u = 0; u < OCT; ++u) P[obase + u * opl] = acc[u];

    // ---- fused BN stats: wave shuffle reduce -> LDS -> global atomics ----
    __shared__ float sm[OCT], sq[OCT];
    if (threadIdx.x < OCT) { sm[threadIdx.x] = 0.f; sq[threadIdx.x] = 0.f; }
    __syncthreads();
#pragma unroll
    for (int u = 0; u < OCT; ++u) {
        float a = acc[u], b2 = acc[u] * acc[u];
#pragma unroll
        for (int o2 = 32; o2 > 0; o2 >>= 1) {
            a += __shfl_down(a, o2);
            b2 += __shfl_down(b2, o2);
        }
        if ((threadIdx.x & 63) == 0) { atomicAdd(&sm[u], a); atomicAdd(&sq[u], b2); }
    }
    __syncthreads();
    if (threadIdx.x < OCT) {
        atomicAdd(&bnt[(oc0 + threadIdx.x) * 2],     sm[threadIdx.x]);
        atomicAdd(&bnt[(oc0 + threadIdx.x) * 2 + 1], sq[threadIdx.x]);
    }
}

// ================= reduce partials / BN stats (verified) =================
__global__ void reduce_bias4(const float4* __restrict__ P, const float* __restrict__ bias,
                             float4* __restrict__ y, int outSize4, int KS, int Co, int HW4) {
    int i = blockIdx.x * 256 + threadIdx.x;
    if (i >= outSize4) return;
    float bv = bias[(i / HW4) % Co];
    float4 s = make_float4(bv, bv, bv, bv);
    for (int ks = 0; ks < KS; ++ks) {
        float4 p = P[(size_t)ks * outSize4 + i];
        s.x += p.x; s.y += p.y; s.z += p.z; s.w += p.w;
    }
    y[i] = s;
}

__global__ void reduce_bias_stats4(const float4* __restrict__ P, const float* __restrict__ bias,
                                   float4* __restrict__ y, float* __restrict__ bnt,
                                   int outSize4, int KS, int Co, int HW4, int nch) {
    int tid = threadIdx.x;
    int i = blockIdx.x * 256 + tid;
    int c = (i / HW4) % Co;
    float bv = bias[c];
    float4 s = make_float4(bv, bv, bv, bv);
    for (int ks = 0; ks < KS; ++ks) {
        float4 p = P[(size_t)ks * outSize4 + i];
        s.x += p.x; s.y += p.y; s.z += p.z; s.w += p.w;
    }
    y[i] = s;
    float ls  = s.x + s.y + s.z + s.w;
    float ls2 = s.x * s.x + s.y * s.y + s.z * s.z + s.w * s.w;
    __shared__ float as[16], aq[16];
    if (tid < 16) { as[tid] = 0.f; aq[tid] = 0.f; }
    __syncthreads();
    int c0 = ((blockIdx.x * 256) / HW4) % Co;
    atomicAdd(&as[c - c0], ls);
    atomicAdd(&aq[c - c0], ls2);
    __syncthreads();
    if (tid < nch) {
        atomicAdd(&bnt[(c0 + tid) * 2],     as[tid]);
        atomicAdd(&bnt[(c0 + tid) * 2 + 1], aq[tid]);
    }
}

// ================= Vector quantizer =================
#define OUT_CL   786432
#define OUT_CB   786433
#define OUT_IDX  786434
#define OUT_MIND 787458

__global__ void vq_main(const float* __restrict__ z, const float* __restrict__ cbT,
                        const float* __restrict__ cb,
                        float* __restrict__ q, float* __restrict__ dout) {
    int r0 = blockIdx.x * 8;
    int tid = threadIdx.x;

    __shared__ float zT[256][8];
    __shared__ float red[256][9];
    __shared__ float zn2[8];
    __shared__ float rd[256];
    __shared__ int   ri[256];
    __shared__ int   bestsh[8];

#pragma unroll
    for (int rr = 0; rr < 8; ++rr) {
        int r = r0 + rr, b = r >> 6, s = r & 63;
        zT[tid][rr] = z[((size_t)(b * 256 + tid)) * 64 + s];
    }
    __syncthreads();
#pragma unroll
    for (int rr = 0; rr < 8; ++rr) { float v = zT[tid][rr]; red[tid][rr] = v * v; }
    __syncthreads();
    for (int off = 128; off > 0; off >>= 1) {
        if (tid < off) {
#pragma unroll
            for (int rr = 0; rr < 8; ++rr) red[tid][rr] += red[tid + off][rr];
        }
        __syncthreads();
    }
    if (tid < 8) zn2[tid] = red[0][tid];
    __syncthreads();

    float d0[8], d1[8];
#pragma unroll
    for (int rr = 0; rr < 8; ++rr) { d0[rr] = 0.f; d1[rr] = 0.f; }
    float cn0 = 0.f, cn1 = 0.f;

    for (int c = 0; c < 256; ++c) {
        float cv0 = cbT[c * 512 + tid];
        float cv1 = cbT[c * 512 + 256 + tid];
        cn0 += cv0 * cv0;
        cn1 += cv1 * cv1;
        float4 za = *(const float4*)&zT[c][0];
        float4 zb = *(const float4*)&zT[c][4];
        const float* zv = (const float*)&za;
        const float* zw = (const float*)&zb;
#pragma unroll
        for (int rr = 0; rr < 4; ++rr) {
            d0[rr]     += zv[rr] * cv0;  d1[rr]     += zv[rr] * cv1;
            d0[rr + 4] += zw[rr] * cv0;  d1[rr + 4] += zw[rr] * cv1;
        }
    }

#pragma unroll
    for (int rr = 0; rr < 8; ++rr) {
        float dist0 = zn2[rr] - 2.f * d0[rr] + cn0;
        float dist1 = zn2[rr] - 2.f * d1[rr] + cn1;
        float bd = dist0; int bi = tid;
        if (dist1 < bd) { bd = dist1; bi = tid + 256; }
        rd[tid] = bd; ri[tid] = bi;
        __syncthreads();
        for (int off = 128; off > 0; off >>= 1) {
            if (tid < off) {
                float od = rd[tid + off]; int oi = ri[tid + off];
                if (od < rd[tid] || (od == rd[tid] && oi < ri[tid])) { rd[tid] = od; ri[tid] = oi; }
            }
            __syncthreads();
        }
        if (tid == 0) {
            int r = r0 + rr;
            bestsh[rr] = ri[0];
            dout[OUT_IDX + r]  = (float)ri[0];
            dout[OUT_MIND + r] = rd[0];
        }
        __syncthreads();
    }

#pragma unroll
    for (int rr = 0; rr < 8; ++rr) {
        int r = r0 + rr, b = r >> 6, s = r & 63;
        q[((size_t)(b * 256 + tid)) * 64 + s] = cb[(size_t)bestsh[rr] * 256 + tid];
    }
}

__global__ void vq_loss(float* __restrict__ dout) {
    int tid = threadIdx.x;
    __shared__ float red[256];
    float s = 0.f;
    for (int i = tid; i < 1024; i += 256) s += dout[OUT_MIND + i];
    red[tid] = s;
    __syncthreads();
    for (int off = 128; off > 0; off >>= 1) {
        if (tid < off) red[tid] += red[tid + off];
        __syncthreads();
    }
    if (tid == 0) {
        float loss = red[0] / 262144.f;
        dout[OUT_CL] = loss;
        dout[OUT_CB] = loss;
    }
}

// ================= Final: BN(D2) + LeakyReLU + 1x1 conv (32->3) + tanh =================
__global__ void final_conv_tanh(const float* __restrict__ hbuf, const float* __restrict__ bnt,
                                const float* __restrict__ g, const float* __restrict__ bt,
                                const float* __restrict__ w3, const float* __restrict__ b3,
                                float* __restrict__ out) {
    __shared__ float sc[32], sh[32];
    int tid = threadIdx.x;
    if (tid < 32) {
        float m = bnt[tid * 2] * (1.f / 262144.f);
        float var = bnt[tid * 2 + 1] * (1.f / 262144.f) - m * m;
        float scale = g[tid] * rsqrtf(var + 1e-5f);
        sc[tid] = scale;
        sh[tid] = bt[tid] - m * scale;
    }
    __syncthreads();
    int idx = blockIdx.x * 256 + tid;
    if (idx >= 16 * 16384) return;
    int hw = idx % 16384;
    int b  = idx / 16384;
    const float* hp = hbuf + ((size_t)b * 32) * 16384 + hw;
    float a0 = b3[0], a1 = b3[1], a2 = b3[2];
#pragma unroll
    for (int c = 0; c < 32; ++c) {
        float v = hp[(size_t)c * 16384];
        v = v * sc[c] + sh[c];
        v = v >= 0.f ? v : LEAK * v;
        a0 += v * w3[c];
        a1 += v * w3[32 + c];
        a2 += v * w3[64 + c];
    }
    size_t ob = ((size_t)b * 3) * 16384 + hw;
    out[ob]             = tanhf(a0);
    out[ob + 16384]     = tanhf(a1);
    out[ob + 2 * 16384] = tanhf(a2);
}

extern "C" void kernel_launch(void* const* d_in, const int* in_sizes, int n_in,
                              void* d_out, int out_size, void* d_ws, size_t ws_size,
                              hipStream_t stream) {
    const float* x      = (const float*)d_in[0];
    const float* enc_w0 = (const float*)d_in[1];
    const float* enc_b0 = (const float*)d_in[2];
    const float* enc_w1 = (const float*)d_in[3];
    const float* enc_b1 = (const float*)d_in[4];
    const float* enc_w2 = (const float*)d_in[5];
    const float* enc_b2 = (const float*)d_in[6];
    const float* enc_w3 = (const float*)d_in[7];
    const float* enc_b3 = (const float*)d_in[8];
    const float* ebn_g0 = (const float*)d_in[9];
    const float* ebn_b0 = (const float*)d_in[10];
    const float* ebn_g1 = (const float*)d_in[11];
    const float* ebn_b1 = (const float*)d_in[12];
    const float* ebn_g2 = (const float*)d_in[13];
    const float* ebn_b2 = (const float*)d_in[14];
    const float* cb     = (const float*)d_in[15];
    const float* dec_w0 = (const float*)d_in[16];
    const float* dec_b0 = (const float*)d_in[17];
    const float* dbn_g0 = (const float*)d_in[18];
    const float* dbn_b0 = (const float*)d_in[19];
    const float* dec_w1 = (const float*)d_in[20];
    const float* dec_b1 = (const float*)d_in[21];
    const float* dbn_g1 = (const float*)d_in[22];
    const float* dbn_b1 = (const float*)d_in[23];
    const float* dec_w2 = (const float*)d_in[24];
    const float* dec_b2 = (const float*)d_in[25];
    const float* dbn_g2 = (const float*)d_in[26];
    const float* dbn_b2 = (const float*)d_in[27];
    const float* dec_w3 = (const float*)d_in[28];
    const float* dec_b3 = (const float*)d_in[29];

    float* out = (float*)d_out;
    float* ws  = (float*)d_ws;

    // ---- workspace (float units); same layout as round 10 (verified) ----
    float*  Y0   = ws;                               // 4194304
    float*  Y1   = ws + 4194304;                     // 2097152
    float*  Y2   = ws + 6291456;                     // 1048576
    float*  Z    = ws + 7340032;                     // 262144
    float*  Q    = ws + 7602176;                     // 262144
    ushort* WH   = (ushort*)(ws + 7864320);          // 2269184 us
    ushort* WL   = (ushort*)(ws + 8998912);          // 2269184 us
    float*  CBT  = ws + 10133504;                    // 131072
    float*  BNT  = ws + 10264576;                    // 6144
    float*  PART = ws + 10270720;                    // 8388608
    float*  D0   = ws + 18659328;                    // 2097152
    float*  D1   = ws + 20756480;                    // 4194304
    float*  D2   = ws + 24950784;                    // 8388608

    dim3 blk(256);

    // ---- prologue (merged) ----
    prep_all<<<8864, blk, 0, stream>>>(enc_w1, enc_w2, enc_w3, dec_w0, dec_w1, dec_w2,
                                       WH, WL, cb, CBT, BNT);

    // ---- encoder ----
    conv4x4<8><<<2048, blk, 0, stream>>>(x, enc_w0, enc_b0, Y0, BNT, 16, 3, 128, 64, 64);

    // enc1: M=128 N=16384 K=1024, KS=4 -> 1024 blocks; B=Y0 raw + BN0
    gemm_mfma<0><<<1024, blk, 0, stream>>>(WH, WL, Y0,
        BNT, ebn_g0, ebn_b0, 1.f / 65536.f, 4, enc_b1, PART, nullptr,
        1, 256, 1024, 256, 4, 2097152, 64, 64, 128, 32, 5, 0, 0, 0, 0);
    reduce_bias_stats4<<<2048, blk, 0, stream>>>((const float4*)PART, enc_b1, (float4*)Y1,
                                                 BNT + 1024, 524288, 4, 128, 256, 1);

    // enc2: M=256 N=4096 K=2048, KS=8 -> 1024 blocks; B=Y1 raw + BN1
    gemm_mfma<0><<<1024, blk, 0, stream>>>(WH + 131072, WL + 131072, Y1,
        BNT + 1024, ebn_g1, ebn_b1, 1.f / 16384.f, 4, enc_b2, PART, nullptr,
        2, 64, 2048, 256, 8, 1048576, 128, 32, 256, 16, 4, 0, 0, 0, 0);
    reduce_bias_stats4<<<1024, blk, 0, stream>>>((const float4*)PART, enc_b2, (float4*)Y2,
                                                 BNT + 2048, 262144, 8, 256, 64, 4);

    // enc3: M=256 N=1024 K=4096, KS=32 -> 1024 blocks; B=Y2 raw + BN2
    gemm_mfma<0><<<1024, blk, 0, stream>>>(WH + 655360, WL + 655360, Y2,
        BNT + 2048, ebn_g2, ebn_b2, 1.f / 4096.f, 4, enc_b3, PART, nullptr,
        2, 16, 4096, 128, 32, 262144, 256, 16, 256, 8, 3, 0, 0, 0, 0);
    reduce_bias4<<<256, blk, 0, stream>>>((const float4*)PART, enc_b3, (float4*)Z, 65536, 32, 256, 16);

    // ---- vector quantizer ----
    vq_main<<<128, blk, 0, stream>>>(Z, CBT, cb, Q, out);
    vq_loss<<<1, blk, 0, stream>>>(out);

    // ---- decoder ----
    // dec0: M=2048 N=1024 K=256, KS=4 -> 1024 blocks; B=Q (no BN)
    gemm_mfma<1><<<1024, blk, 0, stream>>>(WH + 1703936, WL + 1703936, Q,
        nullptr, nullptr, nullptr, 0.f, 0, dec_b0, PART, nullptr,
        16, 16, 256, 64, 4, 2097152, 256, 8, 128, 0, 0, 6, 3, 7, 2);
    reduce_bias_stats4<<<2048, blk, 0, stream>>>((const float4*)PART, dec_b0, (float4*)D0,
                                                 BNT + 3072, 524288, 4, 128, 256, 1);

    // dec1: M=256 N=16384 K=128, KS=2 -> 1024 blocks; B=D0 raw + BN3
    gemm_mfma<1><<<1024, blk, 0, stream>>>(WH + 2228224, WL + 2228224, D0,
        BNT + 3072, dbn_g0, dbn_b0, 1.f / 16384.f, 0, dec_b1, PART, nullptr,
        2, 256, 128, 64, 2, 4194304, 128, 32, 64, 0, 0, 10, 5, 6, 1);
    reduce_bias_stats4<<<4096, blk, 0, stream>>>((const float4*)PART, dec_b1, (float4*)D1,
                                                 BNT + 4096, 1048576, 2, 64, 1024, 1);

    // dec2: M=128 N=65536 K=64, KS=1 -> 1024 blocks; B=D1 raw + BN4; direct write + fused stats
    gemm_mfma<1><<<1024, blk, 0, stream>>>(WH + 2260992, WL + 2260992, D1,
        BNT + 4096, dbn_g1, dbn_b1, 1.f / 65536.f, 0, dec_b2, D2, BNT + 5120,
        1, 1024, 64, 64, 1, 0, 64, 64, 32, 0, 0, 12, 6, 5, 1);

    // final: BN5 + leaky + 1x1 conv + tanh
    final_conv_tanh<<<1024, blk, 0, stream>>>(D2, BNT + 5120, dbn_g2, dbn_b2, dec_w3, dec_b3, out);
}

// Round 13
// 482.910 us; speedup vs baseline: 1.1406x; 1.1406x over previous
//
#include <hip/hip_runtime.h>
#include <math.h>

#define LEAK 0.01f

typedef __bf16 bf16x8 __attribute__((ext_vector_type(8)));
typedef float f32x4 __attribute__((ext_vector_type(4)));
typedef unsigned short ushort;
typedef unsigned int uint32;

struct HL { ushort h, l; };

// split fp32 into bf16 hi + bf16 lo (both RNE): x ~= hi + lo, err ~2^-17 rel
__device__ inline HL split_bf16(float x) {
    unsigned u = __float_as_uint(x);
    unsigned hr = (u + 0x7FFFu + ((u >> 16) & 1u)) >> 16;
    float fh = __uint_as_float(hr << 16);
    float r = x - fh;
    unsigned v = __float_as_uint(r);
    unsigned lr = (v + 0x7FFFu + ((v >> 16) & 1u)) >> 16;
    HL out; out.h = (ushort)hr; out.l = (ushort)lr;
    return out;
}

// ================= staged-B raw load: 64n x 32k fp32 tile, 8 floats/thread (r10, verified) =====
template<int MODE>
__device__ inline void stage_load(float (&pv)[2][4], const float* __restrict__ Bf,
                                  int kbase, int n0, int tid,
                                  int Ci, int Hin, int Ho, int lgHo, int lgHW) {
#pragma unroll
    for (int r = 0; r < 2; ++r) {
        int g = r * 256 + tid;          // 0..511
        int nl = g >> 3, kg = g & 7;
        int n = n0 + nl;
        if (MODE == 0) {
            int k4 = kbase + (kg << 2);
            int ic = k4 >> 4, kh = (k4 >> 2) & 3;
            int ow = n & (Ho - 1), oh = (n >> lgHo) & (Ho - 1), b = n >> (lgHo + lgHo);
            int ih = oh * 2 - 1 + kh;
            int ihc = ih < 0 ? 0 : (ih >= Hin ? Hin - 1 : ih);
            int iwb = ow * 2 - 1;
            size_t base = ((size_t)(b * Ci + ic) * Hin + ihc) * Hin;
#pragma unroll
            for (int e = 0; e < 4; ++e) {
                int iw = iwb + e;
                int iwc = iw < 0 ? 0 : (iw >= Hin ? Hin - 1 : iw);
                pv[r][e] = Bf[base + iwc];
            }
        } else {
            int c = kbase + (kg << 2);
            int b = n >> lgHW, hw = n & ((1 << lgHW) - 1);
            size_t base = (((size_t)(b * Ci + c)) << lgHW) + hw;
            size_t str = (size_t)1 << lgHW;
#pragma unroll
            for (int e = 0; e < 4; ++e) pv[r][e] = Bf[base + e * str];
        }
    }
}

// ================= bf16-split MFMA GEMM (r10 K-loop, verified 460us) =================
// Block tile 128M x 64N, 4 waves of 32M x 64N. K-step 32 (LDS stride 36).
// A: fragment-ordered bf16 hi/lo (r9).  B: raw fp32 + fused BN->leaky->mask->split->pack (r10).
// C = Ah*Bh + Ah*Bl + Al*Bh (r7).  Optional fused output BN-stats for KS==1 MODE 1 (r11).
template<int MODE>
__global__ __launch_bounds__(256, 3) void gemm_mfma(
    const ushort* __restrict__ Ah, const ushort* __restrict__ Al,
    const float* __restrict__ Bf,
    const float* __restrict__ bnt, const float* __restrict__ gamma,
    const float* __restrict__ beta, float invN, int chanShift,
    const float* __restrict__ bias, float* __restrict__ P,
    float* __restrict__ statsOut,
    int Mtiles, int Ntiles, int K, int Kslice, int KS, int outSize,
    int Ci, int Hin, int Co, int Ho, int lgHo,
    int lgHW, int lgHin, int lgCo, int lgk)
{
    __shared__ __align__(16) uint32 Bsp[64 * 36];   // [n][k] packed, stride 36
    __shared__ float scs[256], shs[256];
    __shared__ float st1[32], st2[32];

    int bid = blockIdx.x;
    int ntile = bid % Ntiles; bid /= Ntiles;
    int mtile = bid % Mtiles;
    int ks = bid / Mtiles;
    int tid = threadIdx.x;
    int lane = tid & 63, w = tid >> 6;
    int quad = lane >> 4, tl = lane & 15;
    int n0 = ntile << 6, m0 = mtile << 7, k0 = ks * Kslice;
    int Kt = K >> 5;

    bool useBN = (bnt != nullptr);
    int c0 = k0 >> chanShift;
    if (useBN) {
        int nch = Kslice >> chanShift;
        for (int c = tid; c < nch; c += 256) {
            float m = bnt[(c0 + c) * 2] * invN;
            float var = bnt[(c0 + c) * 2 + 1] * invN - m * m;
            float scale = gamma[c0 + c] * rsqrtf(var + 1e-5f);
            scs[c] = scale;
            shs[c] = beta[c0 + c] - m * scale;
        }
    }
    if (MODE == 1 && statsOut && tid < 32) { st1[tid] = 0.f; st2[tid] = 0.f; }
    __syncthreads();

    f32x4 zero4 = {0.f, 0.f, 0.f, 0.f};
    f32x4 acc[2][4];
#pragma unroll
    for (int mt = 0; mt < 2; ++mt)
#pragma unroll
        for (int nt = 0; nt < 4; ++nt) acc[mt][nt] = zero4;

    float pv[2][4];
    stage_load<MODE>(pv, Bf, k0, n0, tid, Ci, Hin, Ho, lgHo, lgHW);

    for (int kc = 0; kc < Kslice; kc += 32) {
        int kbase = k0 + kc;
        int kt = kbase >> 5;
        // ---- transform + regs -> LDS ----
#pragma unroll
        for (int r = 0; r < 2; ++r) {
            int g = r * 256 + tid;
            int nl = g >> 3, kg = g & 7;
            int k4 = kbase + (kg << 2);
            uint32 pk[4];
            if (MODE == 0) {
                int ic = k4 >> 4, kh = (k4 >> 2) & 3;
                int n = n0 + nl;
                int ow = n & (Ho - 1), oh = (n >> lgHo) & (Ho - 1);
                int ih = oh * 2 - 1 + kh;
                bool rowok = (unsigned)ih < (unsigned)Hin;
                int iwb = ow * 2 - 1;
                float sc_ = useBN ? scs[ic - c0] : 0.f;
                float sh_ = useBN ? shs[ic - c0] : 0.f;
#pragma unroll
                for (int e = 0; e < 4; ++e) {
                    int iw = iwb + e;
                    bool ok = rowok && ((unsigned)iw < (unsigned)Hin);
                    float f = pv[r][e];
                    if (useBN) { f = f * sc_ + sh_; f = f >= 0.f ? f : LEAK * f; }
                    if (!ok) f = 0.f;
                    HL s = split_bf16(f);
                    pk[e] = ((uint32)s.h << 16) | s.l;
                }
            } else {
#pragma unroll
                for (int e = 0; e < 4; ++e) {
                    float f = pv[r][e];
                    if (useBN) {
                        int lc = k4 + e - k0;
                        f = f * scs[lc] + shs[lc];
                        f = f >= 0.f ? f : LEAK * f;
                    }
                    HL s = split_bf16(f);
                    pk[e] = ((uint32)s.h << 16) | s.l;
                }
            }
            *(uint4*)&Bsp[nl * 36 + (kg << 2)] = make_uint4(pk[0], pk[1], pk[2], pk[3]);
        }
        __syncthreads();

        // ---- prefetch next B tile (raw -> loads in flight through the MFMAs) ----
        bool more = (kc + 32) < Kslice;
        float pvn[2][4];
        if (more) stage_load<MODE>(pvn, Bf, kbase + 32, n0, tid, Ci, Hin, Ho, lgHo, lgHW);

        // ---- A fragments: fragment-ordered global, coalesced 16B/lane ----
        bf16x8 afh[2], afl[2];
#pragma unroll
        for (int mt = 0; mt < 2; ++mt) {
            int mtAbs = (m0 >> 4) + (w << 1) + mt;
            size_t abase = (((size_t)mtAbs * Kt + kt) << 6) + lane;
            afh[mt] = *(const bf16x8*)(Ah + abase * 8);
            afl[mt] = *(const bf16x8*)(Al + abase * 8);
        }
        // ---- B fragments: LDS packed -> unpack via v_perm ----
        bf16x8 bfh[4], bfl[4];
#pragma unroll
        for (int nt = 0; nt < 4; ++nt) {
            int base = ((nt << 4) + tl) * 36 + (quad << 3);
            uint4 ua = *(const uint4*)&Bsp[base];
            uint4 ub = *(const uint4*)&Bsp[base + 4];
            union { uint32 u[4]; bf16x8 v; } H, L;
            H.u[0] = __builtin_amdgcn_perm(ua.y, ua.x, 0x07060302u);
            H.u[1] = __builtin_amdgcn_perm(ua.w, ua.z, 0x07060302u);
            H.u[2] = __builtin_amdgcn_perm(ub.y, ub.x, 0x07060302u);
            H.u[3] = __builtin_amdgcn_perm(ub.w, ub.z, 0x07060302u);
            L.u[0] = __builtin_amdgcn_perm(ua.y, ua.x, 0x05040100u);
            L.u[1] = __builtin_amdgcn_perm(ua.w, ua.z, 0x05040100u);
            L.u[2] = __builtin_amdgcn_perm(ub.y, ub.x, 0x05040100u);
            L.u[3] = __builtin_amdgcn_perm(ub.w, ub.z, 0x05040100u);
            bfh[nt] = H.v; bfl[nt] = L.v;
        }
        // ---- 24 MFMAs / wave ----
#pragma unroll
        for (int mt = 0; mt < 2; ++mt)
#pragma unroll
            for (int nt = 0; nt < 4; ++nt) {
                acc[mt][nt] = __builtin_amdgcn_mfma_f32_16x16x32_bf16(afh[mt], bfh[nt], acc[mt][nt], 0, 0, 0);
                acc[mt][nt] = __builtin_amdgcn_mfma_f32_16x16x32_bf16(afh[mt], bfl[nt], acc[mt][nt], 0, 0, 0);
                acc[mt][nt] = __builtin_amdgcn_mfma_f32_16x16x32_bf16(afl[mt], bfh[nt], acc[mt][nt], 0, 0, 0);
            }
        __syncthreads();
        if (more) {
#pragma unroll
            for (int r = 0; r < 2; ++r)
#pragma unroll
                for (int e = 0; e < 4; ++e) pv[r][e] = pvn[r][e];
        }
    }

    // ---- epilogue: D[m = quad*4+reg][n = tl] (verified r7-r10) ----
    float* dst = P + (size_t)ks * outSize;
    if (MODE == 0) {
#pragma unroll
        for (int nt = 0; nt < 4; ++nt) {
            int n = n0 + (nt << 4) + tl;
            int ow = n & (Ho - 1), oh = (n >> lgHo) & (Ho - 1), b = n >> (lgHo + lgHo);
#pragma unroll
            for (int mt = 0; mt < 2; ++mt) {
                int mb = m0 + (w << 5) + (mt << 4) + (quad << 2);
#pragma unroll
                for (int r = 0; r < 4; ++r) {
                    int oc = mb + r;
                    float v = acc[mt][nt][r];
                    if (KS == 1) v += bias[oc];
                    dst[((size_t)(b * Co + oc) * Ho + oh) * Ho + ow] = v;
                }
            }
        }
    } else {
        int kf = 1 << lgk;
        int Ho2 = Hin << lgk;
        float s1p[8], s2p[8];
#pragma unroll
        for (int i = 0; i < 8; ++i) { s1p[i] = 0.f; s2p[i] = 0.f; }
#pragma unroll
        for (int nt = 0; nt < 4; ++nt) {
            int n = n0 + (nt << 4) + tl;
            int b = n >> lgHW, hw = n & ((1 << lgHW) - 1);
            int h = hw >> lgHin, wp = hw & (Hin - 1);
#pragma unroll
            for (int mt = 0; mt < 2; ++mt) {
                int mb = m0 + (w << 5) + (mt << 4) + (quad << 2);
#pragma unroll
                for (int r = 0; r < 4; ++r) {
                    int m = mb + r;
                    int o = m & (Co - 1), ij = m >> lgCo;
                    int ii = ij >> lgk, jj = ij & (kf - 1);
                    float v = acc[mt][nt][r];
                    if (KS == 1) v += bias[o];
                    if (statsOut) { s1p[mt * 4 + r] += v; s2p[mt * 4 + r] += v * v; }
                    dst[((size_t)(b * Co + o) * Ho2 + (h << lgk) + ii) * Ho2 + (wp << lgk) + jj] = v;
                }
            }
        }
        if (statsOut) {
#pragma unroll
            for (int i = 0; i < 8; ++i) {
#pragma unroll
                for (int msk = 1; msk < 16; msk <<= 1) {
                    s1p[i] += __shfl_xor(s1p[i], msk);
                    s2p[i] += __shfl_xor(s2p[i], msk);
                }
            }
            if (tl == 0) {
#pragma unroll
                for (int i = 0; i < 8; ++i) {
                    int o = ((w << 5) + ((i >> 2) << 4) + (quad << 2) + (i & 3)) & (Co - 1);
                    atomicAdd(&st1[o], s1p[i]);
                    atomicAdd(&st2[o], s2p[i]);
                }
            }
            __syncthreads();
            if (tid < 32) {
                atomicAdd(&statsOut[tid * 2],     st1[tid]);
                atomicAdd(&statsOut[tid * 2 + 1], st2[tid]);
            }
        }
    }
}

// ================= merged prologue (r11, verified) =================
__device__ inline int fragaddr(int m, int k, int K) {
    return ((((m >> 4) * (K >> 5) + (k >> 5)) << 9) | (((k >> 3) & 3) << 7) | ((m & 15) << 3) | (k & 7));
}

__global__ void prep_all(const float* __restrict__ w1, const float* __restrict__ w2,
                         const float* __restrict__ w3, const float* __restrict__ d0,
                         const float* __restrict__ d1, const float* __restrict__ d2,
                         ushort* __restrict__ WH, ushort* __restrict__ WL,
                         const float* __restrict__ cb, float* __restrict__ cbT,
                         float* __restrict__ bnt) {
    int idx = blockIdx.x * 256 + threadIdx.x;
    if (idx < 6144) bnt[idx] = 0.f;
    if (idx < 131072) {
        int k = idx & 511, c = idx >> 9;
        cbT[idx] = cb[k * 256 + c];
    }
    if (idx >= 2269184) return;
    float v; int dst;
    if (idx < 131072) {                      // enc1: M=128 K=1024
        int m = idx >> 10, k = idx & 1023;
        v = w1[idx];
        dst = fragaddr(m, k, 1024);
    } else if (idx < 655360) {               // enc2: M=256 K=2048
        int i = idx - 131072;
        int m = i >> 11, k = i & 2047;
        v = w2[i];
        dst = 131072 + fragaddr(m, k, 2048);
    } else if (idx < 1703936) {              // enc3: M=256 K=4096
        int i = idx - 655360;
        int m = i >> 12, k = i & 4095;
        v = w3[i];
        dst = 655360 + fragaddr(m, k, 4096);
    } else if (idx < 2228224) {              // dec0: M=2048 K=256
        int i = idx - 1703936;
        int m = i >> 8, c = i & 255;
        int o = m & 127, ij = m >> 7;
        v = d0[((size_t)c * 128 + o) * 16 + ij];
        dst = 1703936 + fragaddr(m, c, 256);
    } else if (idx < 2260992) {              // dec1: M=256 K=128
        int i = idx - 2228224;
        int m = i >> 7, c = i & 127;
        int o = m & 63, ij = m >> 6;
        v = d1[((size_t)c * 64 + o) * 4 + ij];
        dst = 2228224 + fragaddr(m, c, 128);
    } else {                                 // dec2: M=128 K=64
        int i = idx - 2260992;
        int m = i >> 6, c = i & 63;
        int o = m & 31, ij = m >> 5;
        v = d2[((size_t)c * 32 + o) * 4 + ij];
        dst = 2260992 + fragaddr(m, c, 64);
    }
    HL s = split_bf16(v);
    WH[dst] = s.h; WL[dst] = s.l;
}

// ================= enc0 direct conv (Ci=3) with fused BN stats (r11, verified) =================
template<int OCT>
__global__ __launch_bounds__(256) void conv4x4(
    const float* __restrict__ x, const float* __restrict__ w,
    const float* __restrict__ bias, float* __restrict__ P,
    float* __restrict__ bnt,
    int B, int Ci, int Hin, int Co, int Ho)
{
    int ogn = Co / OCT;
    int ntile = (B * Ho * Ho) >> 8;
    int bid = blockIdx.x;
    int tile = bid % ntile; bid /= ntile;
    int og = bid % ogn;
    int oc0 = og * OCT;

    int px = (tile << 8) + threadIdx.x;
    int ow = px % Ho; int t = px / Ho;
    int oh = t % Ho;  int b = t / Ho;

    int off[16]; float fm[16];
    int ih0 = oh * 2 - 1, iw0 = ow * 2 - 1;
#pragma unroll
    for (int kh = 0; kh < 4; ++kh)
#pragma unroll
        for (int kw = 0; kw < 4; ++kw) {
            int ih = ih0 + kh, iw = iw0 + kw;
            bool ok = (ih >= 0) && (ih < Hin) && (iw >= 0) && (iw < Hin);
            int ihc = ih < 0 ? 0 : (ih >= Hin ? Hin - 1 : ih);
            int iwc = iw < 0 ? 0 : (iw >= Hin ? Hin - 1 : iw);
            off[kh * 4 + kw] = ihc * Hin + iwc;
            fm[kh * 4 + kw] = ok ? 1.f : 0.f;
        }

    float acc[OCT];
#pragma unroll
    for (int u = 0; u < OCT; ++u) acc[u] = bias[oc0 + u];

    const float* xc = x + (size_t)b * Ci * Hin * Hin;
    const float* wi = w + (size_t)oc0 * Ci * 16;
    int HinHin = Hin * Hin;
    for (int ic = 0; ic < Ci; ++ic) {
        float xv[16];
#pragma unroll
        for (int q = 0; q < 16; ++q) xv[q] = xc[off[q]] * fm[q];
#pragma unroll
        for (int u = 0; u < OCT; ++u) {
            const float* wo = wi + (size_t)u * Ci * 16;
            float a = acc[u];
#pragma unroll
            for (int q = 0; q < 16; ++q) a += xv[q] * wo[q];
            acc[u] = a;
        }
        xc += HinHin;
        wi += 16;
    }
    size_t obase = (((size_t)b * Co + oc0) * Ho + oh) * Ho + ow;
    size_t opl = (size_t)Ho * Ho;
#pragma unroll
    for (int u = 0; u < OCT; ++u) P[obase + u * opl] = acc[u];

    __shared__ float sm[OCT], sq[OCT];
    if (threadIdx.x < OCT) { sm[threadIdx.x] = 0.f; sq[threadIdx.x] = 0.f; }
    __syncthreads();
#pragma unroll
    for (int u = 0; u < OCT; ++u) {
        float a = acc[u], b2 = acc[u] * acc[u];
#pragma unroll
        for (int o2 = 32; o2 > 0; o2 >>= 1) {
            a += __shfl_down(a, o2);
            b2 += __shfl_down(b2, o2);
        }
        if ((threadIdx.x & 63) == 0) { atomicAdd(&sm[u], a); atomicAdd(&sq[u], b2); }
    }
    __syncthreads();
    if (threadIdx.x < OCT) {
        atomicAdd(&bnt[(oc0 + threadIdx.x) * 2],     sm[threadIdx.x]);
        atomicAdd(&bnt[(oc0 + threadIdx.x) * 2 + 1], sq[threadIdx.x]);
    }
}

// ================= reduce partials / BN stats (verified) =================
__global__ void reduce_bias4(const float4* __restrict__ P, const float* __restrict__ bias,
                             float4* __restrict__ y, int outSize4, int KS, int Co, int HW4) {
    int i = blockIdx.x * 256 + threadIdx.x;
    if (i >= outSize4) return;
    float bv = bias[(i / HW4) % Co];
    float4 s = make_float4(bv, bv, bv, bv);
    for (int ks = 0; ks < KS; ++ks) {
        float4 p = P[(size_t)ks * outSize4 + i];
        s.x += p.x; s.y += p.y; s.z += p.z; s.w += p.w;
    }
    y[i] = s;
}

__global__ void reduce_bias_stats4(const float4* __restrict__ P, const float* __restrict__ bias,
                                   float4* __restrict__ y, float* __restrict__ bnt,
                                   int outSize4, int KS, int Co, int HW4, int nch) {
    int tid = threadIdx.x;
    int i = blockIdx.x * 256 + tid;
    int c = (i / HW4) % Co;
    float bv = bias[c];
    float4 s = make_float4(bv, bv, bv, bv);
    for (int ks = 0; ks < KS; ++ks) {
        float4 p = P[(size_t)ks * outSize4 + i];
        s.x += p.x; s.y += p.y; s.z += p.z; s.w += p.w;
    }
    y[i] = s;
    float ls  = s.x + s.y + s.z + s.w;
    float ls2 = s.x * s.x + s.y * s.y + s.z * s.z + s.w * s.w;
    __shared__ float as[16], aq[16];
    if (tid < 16) { as[tid] = 0.f; aq[tid] = 0.f; }
    __syncthreads();
    int c0 = ((blockIdx.x * 256) / HW4) % Co;
    atomicAdd(&as[c - c0], ls);
    atomicAdd(&aq[c - c0], ls2);
    __syncthreads();
    if (tid < nch) {
        atomicAdd(&bnt[(c0 + tid) * 2],     as[tid]);
        atomicAdd(&bnt[(c0 + tid) * 2 + 1], aq[tid]);
    }
}

// ================= Vector quantizer (verified) =================
#define OUT_CL   786432
#define OUT_CB   786433
#define OUT_IDX  786434
#define OUT_MIND 787458

__global__ void vq_main(const float* __restrict__ z, const float* __restrict__ cbT,
                        const float* __restrict__ cb,
                        float* __restrict__ q, float* __restrict__ dout) {
    int r0 = blockIdx.x * 8;
    int tid = threadIdx.x;

    __shared__ float zT[256][8];
    __shared__ float red[256][9];
    __shared__ float zn2[8];
    __shared__ float rd[256];
    __shared__ int   ri[256];
    __shared__ int   bestsh[8];

#pragma unroll
    for (int rr = 0; rr < 8; ++rr) {
        int r = r0 + rr, b = r >> 6, s = r & 63;
        zT[tid][rr] = z[((size_t)(b * 256 + tid)) * 64 + s];
    }
    __syncthreads();
#pragma unroll
    for (int rr = 0; rr < 8; ++rr) { float v = zT[tid][rr]; red[tid][rr] = v * v; }
    __syncthreads();
    for (int off = 128; off > 0; off >>= 1) {
        if (tid < off) {
#pragma unroll
            for (int rr = 0; rr < 8; ++rr) red[tid][rr] += red[tid + off][rr];
        }
        __syncthreads();
    }
    if (tid < 8) zn2[tid] = red[0][tid];
    __syncthreads();

    float d0[8], d1[8];
#pragma unroll
    for (int rr = 0; rr < 8; ++rr) { d0[rr] = 0.f; d1[rr] = 0.f; }
    float cn0 = 0.f, cn1 = 0.f;

    for (int c = 0; c < 256; ++c) {
        float cv0 = cbT[c * 512 + tid];
        float cv1 = cbT[c * 512 + 256 + tid];
        cn0 += cv0 * cv0;
        cn1 += cv1 * cv1;
        float4 za = *(const float4*)&zT[c][0];
        float4 zb = *(const float4*)&zT[c][4];
        const float* zv = (const float*)&za;
        const float* zw = (const float*)&zb;
#pragma unroll
        for (int rr = 0; rr < 4; ++rr) {
            d0[rr]     += zv[rr] * cv0;  d1[rr]     += zv[rr] * cv1;
            d0[rr + 4] += zw[rr] * cv0;  d1[rr + 4] += zw[rr] * cv1;
        }
    }

#pragma unroll
    for (int rr = 0; rr < 8; ++rr) {
        float dist0 = zn2[rr] - 2.f * d0[rr] + cn0;
        float dist1 = zn2[rr] - 2.f * d1[rr] + cn1;
        float bd = dist0; int bi = tid;
        if (dist1 < bd) { bd = dist1; bi = tid + 256; }
        rd[tid] = bd; ri[tid] = bi;
        __syncthreads();
        for (int off = 128; off > 0; off >>= 1) {
            if (tid < off) {
                float od = rd[tid + off]; int oi = ri[tid + off];
                if (od < rd[tid] || (od == rd[tid] && oi < ri[tid])) { rd[tid] = od; ri[tid] = oi; }
            }
            __syncthreads();
        }
        if (tid == 0) {
            int r = r0 + rr;
            bestsh[rr] = ri[0];
            dout[OUT_IDX + r]  = (float)ri[0];
            dout[OUT_MIND + r] = rd[0];
        }
        __syncthreads();
    }

#pragma unroll
    for (int rr = 0; rr < 8; ++rr) {
        int r = r0 + rr, b = r >> 6, s = r & 63;
        q[((size_t)(b * 256 + tid)) * 64 + s] = cb[(size_t)bestsh[rr] * 256 + tid];
    }
}

__global__ void vq_loss(float* __restrict__ dout) {
    int tid = threadIdx.x;
    __shared__ float red[256];
    float s = 0.f;
    for (int i = tid; i < 1024; i += 256) s += dout[OUT_MIND + i];
    red[tid] = s;
    __syncthreads();
    for (int off = 128; off > 0; off >>= 1) {
        if (tid < off) red[tid] += red[tid + off];
        __syncthreads();
    }
    if (tid == 0) {
        float loss = red[0] / 262144.f;
        dout[OUT_CL] = loss;
        dout[OUT_CB] = loss;
    }
}

// ================= Final: BN(D2) + LeakyReLU + 1x1 conv (32->3) + tanh (verified) ==========
__global__ void final_conv_tanh(const float* __restrict__ hbuf, const float* __restrict__ bnt,
                                const float* __restrict__ g, const float* __restrict__ bt,
                                const float* __restrict__ w3, const float* __restrict__ b3,
                                float* __restrict__ out) {
    __shared__ float sc[32], sh[32];
    int tid = threadIdx.x;
    if (tid < 32) {
        float m = bnt[tid * 2] * (1.f / 262144.f);
        float var = bnt[tid * 2 + 1] * (1.f / 262144.f) - m * m;
        float scale = g[tid] * rsqrtf(var + 1e-5f);
        sc[tid] = scale;
        sh[tid] = bt[tid] - m * scale;
    }
    __syncthreads();
    int idx = blockIdx.x * 256 + tid;
    if (idx >= 16 * 16384) return;
    int hw = idx % 16384;
    int b  = idx / 16384;
    const float* hp = hbuf + ((size_t)b * 32) * 16384 + hw;
    float a0 = b3[0], a1 = b3[1], a2 = b3[2];
#pragma unroll
    for (int c = 0; c < 32; ++c) {
        float v = hp[(size_t)c * 16384];
        v = v * sc[c] + sh[c];
        v = v >= 0.f ? v : LEAK * v;
        a0 += v * w3[c];
        a1 += v * w3[32 + c];
        a2 += v * w3[64 + c];
    }
    size_t ob = ((size_t)b * 3) * 16384 + hw;
    out[ob]             = tanhf(a0);
    out[ob + 16384]     = tanhf(a1);
    out[ob + 2 * 16384] = tanhf(a2);
}

extern "C" void kernel_launch(void* const* d_in, const int* in_sizes, int n_in,
                              void* d_out, int out_size, void* d_ws, size_t ws_size,
                              hipStream_t stream) {
    const float* x      = (const float*)d_in[0];
    const float* enc_w0 = (const float*)d_in[1];
    const float* enc_b0 = (const float*)d_in[2];
    const float* enc_w1 = (const float*)d_in[3];
    const float* enc_b1 = (const float*)d_in[4];
    const float* enc_w2 = (const float*)d_in[5];
    const float* enc_b2 = (const float*)d_in[6];
    const float* enc_w3 = (const float*)d_in[7];
    const float* enc_b3 = (const float*)d_in[8];
    const float* ebn_g0 = (const float*)d_in[9];
    const float* ebn_b0 = (const float*)d_in[10];
    const float* ebn_g1 = (const float*)d_in[11];
    const float* ebn_b1 = (const float*)d_in[12];
    const float* ebn_g2 = (const float*)d_in[13];
    const float* ebn_b2 = (const float*)d_in[14];
    const float* cb     = (const float*)d_in[15];
    const float* dec_w0 = (const float*)d_in[16];
    const float* dec_b0 = (const float*)d_in[17];
    const float* dbn_g0 = (const float*)d_in[18];
    const float* dbn_b0 = (const float*)d_in[19];
    const float* dec_w1 = (const float*)d_in[20];
    const float* dec_b1 = (const float*)d_in[21];
    const float* dbn_g1 = (const float*)d_in[22];
    const float* dbn_b1 = (const float*)d_in[23];
    const float* dec_w2 = (const float*)d_in[24];
    const float* dec_b2 = (const float*)d_in[25];
    const float* dbn_g2 = (const float*)d_in[26];
    const float* dbn_b2 = (const float*)d_in[27];
    const float* dec_w3 = (const float*)d_in[28];
    const float* dec_b3 = (const float*)d_in[29];

    float* out = (float*)d_out;
    float* ws  = (float*)d_ws;

    // ---- workspace (float units); same layout as round 10 (verified) ----
    float*  Y0   = ws;                               // 4194304
    float*  Y1   = ws + 4194304;                     // 2097152
    float*  Y2   = ws + 6291456;                     // 1048576
    float*  Z    = ws + 7340032;                     // 262144
    float*  Q    = ws + 7602176;                     // 262144
    ushort* WH   = (ushort*)(ws + 7864320);          // 2269184 us
    ushort* WL   = (ushort*)(ws + 8998912);          // 2269184 us
    float*  CBT  = ws + 10133504;                    // 131072
    float*  BNT  = ws + 10264576;                    // 6144
    float*  PART = ws + 10270720;                    // 8388608
    float*  D0   = ws + 18659328;                    // 2097152
    float*  D1   = ws + 20756480;                    // 4194304
    float*  D2   = ws + 24950784;                    // 8388608

    dim3 blk(256);

    // ---- prologue (merged) ----
    prep_all<<<8864, blk, 0, stream>>>(enc_w1, enc_w2, enc_w3, dec_w0, dec_w1, dec_w2,
                                       WH, WL, cb, CBT, BNT);

    // ---- encoder ----
    conv4x4<8><<<2048, blk, 0, stream>>>(x, enc_w0, enc_b0, Y0, BNT, 16, 3, 128, 64, 64);

    // enc1: M=128 N=16384 K=1024, KS=4 -> 1024 blocks; B=Y0 raw + BN0
    gemm_mfma<0><<<1024, blk, 0, stream>>>(WH, WL, Y0,
        BNT, ebn_g0, ebn_b0, 1.f / 65536.f, 4, enc_b1, PART, nullptr,
        1, 256, 1024, 256, 4, 2097152, 64, 64, 128, 32, 5, 0, 0, 0, 0);
    reduce_bias_stats4<<<2048, blk, 0, stream>>>((const float4*)PART, enc_b1, (float4*)Y1,
                                                 BNT + 1024, 524288, 4, 128, 256, 1);

    // enc2: M=256 N=4096 K=2048, KS=8 -> 1024 blocks; B=Y1 raw + BN1
    gemm_mfma<0><<<1024, blk, 0, stream>>>(WH + 131072, WL + 131072, Y1,
        BNT + 1024, ebn_g1, ebn_b1, 1.f / 16384.f, 4, enc_b2, PART, nullptr,
        2, 64, 2048, 256, 8, 1048576, 128, 32, 256, 16, 4, 0, 0, 0, 0);
    reduce_bias_stats4<<<1024, blk, 0, stream>>>((const float4*)PART, enc_b2, (float4*)Y2,
                                                 BNT + 2048, 262144, 8, 256, 64, 4);

    // enc3: M=256 N=1024 K=4096, KS=32 -> 1024 blocks; B=Y2 raw + BN2
    gemm_mfma<0><<<1024, blk, 0, stream>>>(WH + 655360, WL + 655360, Y2,
        BNT + 2048, ebn_g2, ebn_b2, 1.f / 4096.f, 4, enc_b3, PART, nullptr,
        2, 16, 4096, 128, 32, 262144, 256, 16, 256, 8, 3, 0, 0, 0, 0);
    reduce_bias4<<<256, blk, 0, stream>>>((const float4*)PART, enc_b3, (float4*)Z, 65536, 32, 256, 16);

    // ---- vector quantizer ----
    vq_main<<<128, blk, 0, stream>>>(Z, CBT, cb, Q, out);
    vq_loss<<<1, blk, 0, stream>>>(out);

    // ---- decoder ----
    // dec0: M=2048 N=1024 K=256, KS=4 -> 1024 blocks; B=Q (no BN)
    gemm_mfma<1><<<1024, blk, 0, stream>>>(WH + 1703936, WL + 1703936, Q,
        nullptr, nullptr, nullptr, 0.f, 0, dec_b0, PART, nullptr,
        16, 16, 256, 64, 4, 2097152, 256, 8, 128, 0, 0, 6, 3, 7, 2);
    reduce_bias_stats4<<<2048, blk, 0, stream>>>((const float4*)PART, dec_b0, (float4*)D0,
                                                 BNT + 3072, 524288, 4, 128, 256, 1);

    // dec1: M=256 N=16384 K=128, KS=2 -> 1024 blocks; B=D0 raw + BN3
    gemm_mfma<1><<<1024, blk, 0, stream>>>(WH + 2228224, WL + 2228224, D0,
        BNT + 3072, dbn_g0, dbn_b0, 1.f / 16384.f, 0, dec_b1, PART, nullptr,
        2, 256, 128, 64, 2, 4194304, 128, 32, 64, 0, 0, 10, 5, 6, 1);
    reduce_bias_stats4<<<4096, blk, 0, stream>>>((const float4*)PART, dec_b1, (float4*)D1,
                                                 BNT + 4096, 1048576, 2, 64, 1024, 1);

    // dec2: M=128 N=65536 K=64, KS=1 -> 1024 blocks; B=D1 raw + BN4; direct write + fused stats
    gemm_mfma<1><<<1024, blk, 0, stream>>>(WH + 2260992, WL + 2260992, D1,
        BNT + 4096, dbn_g1, dbn_b1, 1.f / 65536.f, 0, dec_b2, D2, BNT + 5120,
        1, 1024, 64, 64, 1, 0, 64, 64, 32, 0, 0, 12, 6, 5, 1);

    // final: BN5 + leaky + 1x1 conv + tanh
    final_conv_tanh<<<1024, blk, 0, stream>>>(D2, BNT + 5120, dbn_g2, dbn_b2, dec_w3, dec_b3, out);
}

// Round 14
// 476.716 us; speedup vs baseline: 1.1554x; 1.0130x over previous
//
#include <hip/hip_runtime.h>
#include <math.h>

#define LEAK 0.01f

typedef __bf16 bf16x8 __attribute__((ext_vector_type(8)));
typedef float f32x4 __attribute__((ext_vector_type(4)));
typedef unsigned short ushort;
typedef unsigned int uint32;

struct HL { ushort h, l; };

// split fp32 into bf16 hi + bf16 lo (both RNE): x ~= hi + lo, err ~2^-17 rel
__device__ inline HL split_bf16(float x) {
    unsigned u = __float_as_uint(x);
    unsigned hr = (u + 0x7FFFu + ((u >> 16) & 1u)) >> 16;
    float fh = __uint_as_float(hr << 16);
    float r = x - fh;
    unsigned v = __float_as_uint(r);
    unsigned lr = (v + 0x7FFFu + ((v >> 16) & 1u)) >> 16;
    HL out; out.h = (ushort)hr; out.l = (ushort)lr;
    return out;
}

// ================= staged-B raw load: 64n x 32k fp32 tile, n-major lane map =================
// lane map: nl = g & 63 (consecutive lanes -> consecutive pixels, coalesced), kg = g >> 6.
template<int MODE>
__device__ inline void stage_load(float (&pv)[2][4], const float* __restrict__ Bf,
                                  int kbase, int n0, int tid,
                                  int Ci, int Hin, int Ho, int lgHo, int lgHW) {
#pragma unroll
    for (int r = 0; r < 2; ++r) {
        int g = r * 256 + tid;          // 0..511
        int nl = g & 63, kg = g >> 6;   // n-major: wave = one kg, 64 consecutive n
        int n = n0 + nl;
        if (MODE == 0) {
            int k4 = kbase + (kg << 2);
            int ic = k4 >> 4, kh = (k4 >> 2) & 3;
            int ow = n & (Ho - 1), oh = (n >> lgHo) & (Ho - 1), b = n >> (lgHo + lgHo);
            int ih = oh * 2 - 1 + kh;
            int ihc = ih < 0 ? 0 : (ih >= Hin ? Hin - 1 : ih);
            int iwb = ow * 2 - 1;
            size_t base = ((size_t)(b * Ci + ic) * Hin + ihc) * Hin;
#pragma unroll
            for (int e = 0; e < 4; ++e) {
                int iw = iwb + e;
                int iwc = iw < 0 ? 0 : (iw >= Hin ? Hin - 1 : iw);
                pv[r][e] = Bf[base + iwc];
            }
        } else {
            int c = kbase + (kg << 2);
            int b = n >> lgHW, hw = n & ((1 << lgHW) - 1);
            size_t base = (((size_t)(b * Ci + c)) << lgHW) + hw;
            size_t str = (size_t)1 << lgHW;
#pragma unroll
            for (int e = 0; e < 4; ++e) pv[r][e] = Bf[base + e * str];
        }
    }
}

// ================= bf16-split MFMA GEMM (r10 K-loop; n-major staging) =================
// Block tile 128M x 64N, 4 waves of 32M x 64N. K-step 32 (LDS stride 36).
// A: fragment-ordered bf16 hi/lo (r9).  B: raw fp32 + fused BN->leaky->mask->split->pack (r10).
// C = Ah*Bh + Ah*Bl + Al*Bh (r7).  Optional fused output BN-stats for KS==1 MODE 1 (r11).
template<int MODE>
__global__ __launch_bounds__(256, 3) void gemm_mfma(
    const ushort* __restrict__ Ah, const ushort* __restrict__ Al,
    const float* __restrict__ Bf,
    const float* __restrict__ bnt, const float* __restrict__ gamma,
    const float* __restrict__ beta, float invN, int chanShift,
    const float* __restrict__ bias, float* __restrict__ P,
    float* __restrict__ statsOut,
    int Mtiles, int Ntiles, int K, int Kslice, int KS, int outSize,
    int Ci, int Hin, int Co, int Ho, int lgHo,
    int lgHW, int lgHin, int lgCo, int lgk)
{
    __shared__ __align__(16) uint32 Bsp[64 * 36];   // [n][k] packed, stride 36
    __shared__ float scs[256], shs[256];
    __shared__ float st1[32], st2[32];

    int bid = blockIdx.x;
    int ntile = bid % Ntiles; bid /= Ntiles;
    int mtile = bid % Mtiles;
    int ks = bid / Mtiles;
    int tid = threadIdx.x;
    int lane = tid & 63, w = tid >> 6;
    int quad = lane >> 4, tl = lane & 15;
    int n0 = ntile << 6, m0 = mtile << 7, k0 = ks * Kslice;
    int Kt = K >> 5;

    bool useBN = (bnt != nullptr);
    int c0 = k0 >> chanShift;
    if (useBN) {
        int nch = Kslice >> chanShift;
        for (int c = tid; c < nch; c += 256) {
            float m = bnt[(c0 + c) * 2] * invN;
            float var = bnt[(c0 + c) * 2 + 1] * invN - m * m;
            float scale = gamma[c0 + c] * rsqrtf(var + 1e-5f);
            scs[c] = scale;
            shs[c] = beta[c0 + c] - m * scale;
        }
    }
    if (MODE == 1 && statsOut && tid < 32) { st1[tid] = 0.f; st2[tid] = 0.f; }
    __syncthreads();

    f32x4 zero4 = {0.f, 0.f, 0.f, 0.f};
    f32x4 acc[2][4];
#pragma unroll
    for (int mt = 0; mt < 2; ++mt)
#pragma unroll
        for (int nt = 0; nt < 4; ++nt) acc[mt][nt] = zero4;

    float pv[2][4];
    stage_load<MODE>(pv, Bf, k0, n0, tid, Ci, Hin, Ho, lgHo, lgHW);

    for (int kc = 0; kc < Kslice; kc += 32) {
        int kbase = k0 + kc;
        int kt = kbase >> 5;
        // ---- transform + regs -> LDS (n-major map, same LDS layout) ----
#pragma unroll
        for (int r = 0; r < 2; ++r) {
            int g = r * 256 + tid;
            int nl = g & 63, kg = g >> 6;
            int k4 = kbase + (kg << 2);
            uint32 pk[4];
            if (MODE == 0) {
                int ic = k4 >> 4, kh = (k4 >> 2) & 3;
                int n = n0 + nl;
                int ow = n & (Ho - 1), oh = (n >> lgHo) & (Ho - 1);
                int ih = oh * 2 - 1 + kh;
                bool rowok = (unsigned)ih < (unsigned)Hin;
                int iwb = ow * 2 - 1;
                float sc_ = useBN ? scs[ic - c0] : 0.f;
                float sh_ = useBN ? shs[ic - c0] : 0.f;
#pragma unroll
                for (int e = 0; e < 4; ++e) {
                    int iw = iwb + e;
                    bool ok = rowok && ((unsigned)iw < (unsigned)Hin);
                    float f = pv[r][e];
                    if (useBN) { f = f * sc_ + sh_; f = f >= 0.f ? f : LEAK * f; }
                    if (!ok) f = 0.f;
                    HL s = split_bf16(f);
                    pk[e] = ((uint32)s.h << 16) | s.l;
                }
            } else {
#pragma unroll
                for (int e = 0; e < 4; ++e) {
                    float f = pv[r][e];
                    if (useBN) {
                        int lc = k4 + e - k0;
                        f = f * scs[lc] + shs[lc];
                        f = f >= 0.f ? f : LEAK * f;
                    }
                    HL s = split_bf16(f);
                    pk[e] = ((uint32)s.h << 16) | s.l;
                }
            }
            *(uint4*)&Bsp[nl * 36 + (kg << 2)] = make_uint4(pk[0], pk[1], pk[2], pk[3]);
        }
        __syncthreads();

        // ---- prefetch next B tile (raw -> loads in flight through the MFMAs) ----
        bool more = (kc + 32) < Kslice;
        float pvn[2][4];
        if (more) stage_load<MODE>(pvn, Bf, kbase + 32, n0, tid, Ci, Hin, Ho, lgHo, lgHW);

        // ---- A fragments: fragment-ordered global, coalesced 16B/lane ----
        bf16x8 afh[2], afl[2];
#pragma unroll
        for (int mt = 0; mt < 2; ++mt) {
            int mtAbs = (m0 >> 4) + (w << 1) + mt;
            size_t abase = (((size_t)mtAbs * Kt + kt) << 6) + lane;
            afh[mt] = *(const bf16x8*)(Ah + abase * 8);
            afl[mt] = *(const bf16x8*)(Al + abase * 8);
        }
        // ---- B fragments: LDS packed -> unpack via v_perm ----
        bf16x8 bfh[4], bfl[4];
#pragma unroll
        for (int nt = 0; nt < 4; ++nt) {
            int base = ((nt << 4) + tl) * 36 + (quad << 3);
            uint4 ua = *(const uint4*)&Bsp[base];
            uint4 ub = *(const uint4*)&Bsp[base + 4];
            union { uint32 u[4]; bf16x8 v; } H, L;
            H.u[0] = __builtin_amdgcn_perm(ua.y, ua.x, 0x07060302u);
            H.u[1] = __builtin_amdgcn_perm(ua.w, ua.z, 0x07060302u);
            H.u[2] = __builtin_amdgcn_perm(ub.y, ub.x, 0x07060302u);
            H.u[3] = __builtin_amdgcn_perm(ub.w, ub.z, 0x07060302u);
            L.u[0] = __builtin_amdgcn_perm(ua.y, ua.x, 0x05040100u);
            L.u[1] = __builtin_amdgcn_perm(ua.w, ua.z, 0x05040100u);
            L.u[2] = __builtin_amdgcn_perm(ub.y, ub.x, 0x05040100u);
            L.u[3] = __builtin_amdgcn_perm(ub.w, ub.z, 0x05040100u);
            bfh[nt] = H.v; bfl[nt] = L.v;
        }
        // ---- 24 MFMAs / wave ----
#pragma unroll
        for (int mt = 0; mt < 2; ++mt)
#pragma unroll
            for (int nt = 0; nt < 4; ++nt) {
                acc[mt][nt] = __builtin_amdgcn_mfma_f32_16x16x32_bf16(afh[mt], bfh[nt], acc[mt][nt], 0, 0, 0);
                acc[mt][nt] = __builtin_amdgcn_mfma_f32_16x16x32_bf16(afh[mt], bfl[nt], acc[mt][nt], 0, 0, 0);
                acc[mt][nt] = __builtin_amdgcn_mfma_f32_16x16x32_bf16(afl[mt], bfh[nt], acc[mt][nt], 0, 0, 0);
            }
        __syncthreads();
        if (more) {
#pragma unroll
            for (int r = 0; r < 2; ++r)
#pragma unroll
                for (int e = 0; e < 4; ++e) pv[r][e] = pvn[r][e];
        }
    }

    // ---- epilogue: D[m = quad*4+reg][n = tl] (verified r7-r13) ----
    float* dst = P + (size_t)ks * outSize;
    if (MODE == 0) {
#pragma unroll
        for (int nt = 0; nt < 4; ++nt) {
            int n = n0 + (nt << 4) + tl;
            int ow = n & (Ho - 1), oh = (n >> lgHo) & (Ho - 1), b = n >> (lgHo + lgHo);
#pragma unroll
            for (int mt = 0; mt < 2; ++mt) {
                int mb = m0 + (w << 5) + (mt << 4) + (quad << 2);
#pragma unroll
                for (int r = 0; r < 4; ++r) {
                    int oc = mb + r;
                    float v = acc[mt][nt][r];
                    if (KS == 1) v += bias[oc];
                    dst[((size_t)(b * Co + oc) * Ho + oh) * Ho + ow] = v;
                }
            }
        }
    } else {
        int kf = 1 << lgk;
        int Ho2 = Hin << lgk;
        float s1p[8], s2p[8];
#pragma unroll
        for (int i = 0; i < 8; ++i) { s1p[i] = 0.f; s2p[i] = 0.f; }
#pragma unroll
        for (int nt = 0; nt < 4; ++nt) {
            int n = n0 + (nt << 4) + tl;
            int b = n >> lgHW, hw = n & ((1 << lgHW) - 1);
            int h = hw >> lgHin, wp = hw & (Hin - 1);
#pragma unroll
            for (int mt = 0; mt < 2; ++mt) {
                int mb = m0 + (w << 5) + (mt << 4) + (quad << 2);
#pragma unroll
                for (int r = 0; r < 4; ++r) {
                    int m = mb + r;
                    int o = m & (Co - 1), ij = m >> lgCo;
                    int ii = ij >> lgk, jj = ij & (kf - 1);
                    float v = acc[mt][nt][r];
                    if (KS == 1) v += bias[o];
                    if (statsOut) { s1p[mt * 4 + r] += v; s2p[mt * 4 + r] += v * v; }
                    dst[((size_t)(b * Co + o) * Ho2 + (h << lgk) + ii) * Ho2 + (wp << lgk) + jj] = v;
                }
            }
        }
        if (statsOut) {
#pragma unroll
            for (int i = 0; i < 8; ++i) {
#pragma unroll
                for (int msk = 1; msk < 16; msk <<= 1) {
                    s1p[i] += __shfl_xor(s1p[i], msk);
                    s2p[i] += __shfl_xor(s2p[i], msk);
                }
            }
            if (tl == 0) {
#pragma unroll
                for (int i = 0; i < 8; ++i) {
                    int o = ((w << 5) + ((i >> 2) << 4) + (quad << 2) + (i & 3)) & (Co - 1);
                    atomicAdd(&st1[o], s1p[i]);
                    atomicAdd(&st2[o], s2p[i]);
                }
            }
            __syncthreads();
            if (tid < 32) {
                atomicAdd(&statsOut[tid * 2],     st1[tid]);
                atomicAdd(&statsOut[tid * 2 + 1], st2[tid]);
            }
        }
    }
}

// ================= merged prologue (r11, verified) =================
__device__ inline int fragaddr(int m, int k, int K) {
    return ((((m >> 4) * (K >> 5) + (k >> 5)) << 9) | (((k >> 3) & 3) << 7) | ((m & 15) << 3) | (k & 7));
}

__global__ void prep_all(const float* __restrict__ w1, const float* __restrict__ w2,
                         const float* __restrict__ w3, const float* __restrict__ d0,
                         const float* __restrict__ d1, const float* __restrict__ d2,
                         ushort* __restrict__ WH, ushort* __restrict__ WL,
                         const float* __restrict__ cb, float* __restrict__ cbT,
                         float* __restrict__ bnt) {
    int idx = blockIdx.x * 256 + threadIdx.x;
    if (idx < 6144) bnt[idx] = 0.f;
    if (idx < 131072) {
        int k = idx & 511, c = idx >> 9;
        cbT[idx] = cb[k * 256 + c];
    }
    if (idx >= 2269184) return;
    float v; int dst;
    if (idx < 131072) {                      // enc1: M=128 K=1024
        int m = idx >> 10, k = idx & 1023;
        v = w1[idx];
        dst = fragaddr(m, k, 1024);
    } else if (idx < 655360) {               // enc2: M=256 K=2048
        int i = idx - 131072;
        int m = i >> 11, k = i & 2047;
        v = w2[i];
        dst = 131072 + fragaddr(m, k, 2048);
    } else if (idx < 1703936) {              // enc3: M=256 K=4096
        int i = idx - 655360;
        int m = i >> 12, k = i & 4095;
        v = w3[i];
        dst = 655360 + fragaddr(m, k, 4096);
    } else if (idx < 2228224) {              // dec0: M=2048 K=256
        int i = idx - 1703936;
        int m = i >> 8, c = i & 255;
        int o = m & 127, ij = m >> 7;
        v = d0[((size_t)c * 128 + o) * 16 + ij];
        dst = 1703936 + fragaddr(m, c, 256);
    } else if (idx < 2260992) {              // dec1: M=256 K=128
        int i = idx - 2228224;
        int m = i >> 7, c = i & 127;
        int o = m & 63, ij = m >> 6;
        v = d1[((size_t)c * 64 + o) * 4 + ij];
        dst = 2228224 + fragaddr(m, c, 128);
    } else {                                 // dec2: M=128 K=64
        int i = idx - 2260992;
        int m = i >> 6, c = i & 63;
        int o = m & 31, ij = m >> 5;
        v = d2[((size_t)c * 32 + o) * 4 + ij];
        dst = 2260992 + fragaddr(m, c, 64);
    }
    HL s = split_bf16(v);
    WH[dst] = s.h; WL[dst] = s.l;
}

// ================= enc0 direct conv (Ci=3) with fused BN stats (r11, verified) =================
template<int OCT>
__global__ __launch_bounds__(256) void conv4x4(
    const float* __restrict__ x, const float* __restrict__ w,
    const float* __restrict__ bias, float* __restrict__ P,
    float* __restrict__ bnt,
    int B, int Ci, int Hin, int Co, int Ho)
{
    int ogn = Co / OCT;
    int ntile = (B * Ho * Ho) >> 8;
    int bid = blockIdx.x;
    int tile = bid % ntile; bid /= ntile;
    int og = bid % ogn;
    int oc0 = og * OCT;

    int px = (tile << 8) + threadIdx.x;
    int ow = px % Ho; int t = px / Ho;
    int oh = t % Ho;  int b = t / Ho;

    int off[16]; float fm[16];
    int ih0 = oh * 2 - 1, iw0 = ow * 2 - 1;
#pragma unroll
    for (int kh = 0; kh < 4; ++kh)
#pragma unroll
        for (int kw = 0; kw < 4; ++kw) {
            int ih = ih0 + kh, iw = iw0 + kw;
            bool ok = (ih >= 0) && (ih < Hin) && (iw >= 0) && (iw < Hin);
            int ihc = ih < 0 ? 0 : (ih >= Hin ? Hin - 1 : ih);
            int iwc = iw < 0 ? 0 : (iw >= Hin ? Hin - 1 : iw);
            off[kh * 4 + kw] = ihc * Hin + iwc;
            fm[kh * 4 + kw] = ok ? 1.f : 0.f;
        }

    float acc[OCT];
#pragma unroll
    for (int u = 0; u < OCT; ++u) acc[u] = bias[oc0 + u];

    const float* xc = x + (size_t)b * Ci * Hin * Hin;
    const float* wi = w + (size_t)oc0 * Ci * 16;
    int HinHin = Hin * Hin;
    for (int ic = 0; ic < Ci; ++ic) {
        float xv[16];
#pragma unroll
        for (int q = 0; q < 16; ++q) xv[q] = xc[off[q]] * fm[q];
#pragma unroll
        for (int u = 0; u < OCT; ++u) {
            const float* wo = wi + (size_t)u * Ci * 16;
            float a = acc[u];
#pragma unroll
            for (int q = 0; q < 16; ++q) a += xv[q] * wo[q];
            acc[u] = a;
        }
        xc += HinHin;
        wi += 16;
    }
    size_t obase = (((size_t)b * Co + oc0) * Ho + oh) * Ho + ow;
    size_t opl = (size_t)Ho * Ho;
#pragma unroll
    for (int u = 0; u < OCT; ++u) P[obase + u * opl] = acc[u];

    __shared__ float sm[OCT], sq[OCT];
    if (threadIdx.x < OCT) { sm[threadIdx.x] = 0.f; sq[threadIdx.x] = 0.f; }
    __syncthreads();
#pragma unroll
    for (int u = 0; u < OCT; ++u) {
        float a = acc[u], b2 = acc[u] * acc[u];
#pragma unroll
        for (int o2 = 32; o2 > 0; o2 >>= 1) {
            a += __shfl_down(a, o2);
            b2 += __shfl_down(b2, o2);
        }
        if ((threadIdx.x & 63) == 0) { atomicAdd(&sm[u], a); atomicAdd(&sq[u], b2); }
    }
    __syncthreads();
    if (threadIdx.x < OCT) {
        atomicAdd(&bnt[(oc0 + threadIdx.x) * 2],     sm[threadIdx.x]);
        atomicAdd(&bnt[(oc0 + threadIdx.x) * 2 + 1], sq[threadIdx.x]);
    }
}

// ================= reduce partials / BN stats (verified) =================
__global__ void reduce_bias4(const float4* __restrict__ P, const float* __restrict__ bias,
                             float4* __restrict__ y, int outSize4, int KS, int Co, int HW4) {
    int i = blockIdx.x * 256 + threadIdx.x;
    if (i >= outSize4) return;
    float bv = bias[(i / HW4) % Co];
    float4 s = make_float4(bv, bv, bv, bv);
    for (int ks = 0; ks < KS; ++ks) {
        float4 p = P[(size_t)ks * outSize4 + i];
        s.x += p.x; s.y += p.y; s.z += p.z; s.w += p.w;
    }
    y[i] = s;
}

__global__ void reduce_bias_stats4(const float4* __restrict__ P, const float* __restrict__ bias,
                                   float4* __restrict__ y, float* __restrict__ bnt,
                                   int outSize4, int KS, int Co, int HW4, int nch) {
    int tid = threadIdx.x;
    int i = blockIdx.x * 256 + tid;
    int c = (i / HW4) % Co;
    float bv = bias[c];
    float4 s = make_float4(bv, bv, bv, bv);
    for (int ks = 0; ks < KS; ++ks) {
        float4 p = P[(size_t)ks * outSize4 + i];
        s.x += p.x; s.y += p.y; s.z += p.z; s.w += p.w;
    }
    y[i] = s;
    float ls  = s.x + s.y + s.z + s.w;
    float ls2 = s.x * s.x + s.y * s.y + s.z * s.z + s.w * s.w;
    __shared__ float as[16], aq[16];
    if (tid < 16) { as[tid] = 0.f; aq[tid] = 0.f; }
    __syncthreads();
    int c0 = ((blockIdx.x * 256) / HW4) % Co;
    atomicAdd(&as[c - c0], ls);
    atomicAdd(&aq[c - c0], ls2);
    __syncthreads();
    if (tid < nch) {
        atomicAdd(&bnt[(c0 + tid) * 2],     as[tid]);
        atomicAdd(&bnt[(c0 + tid) * 2 + 1], aq[tid]);
    }
}

// ================= Vector quantizer (verified) =================
#define OUT_CL   786432
#define OUT_CB   786433
#define OUT_IDX  786434
#define OUT_MIND 787458

__global__ void vq_main(const float* __restrict__ z, const float* __restrict__ cbT,
                        const float* __restrict__ cb,
                        float* __restrict__ q, float* __restrict__ dout) {
    int r0 = blockIdx.x * 8;
    int tid = threadIdx.x;

    __shared__ float zT[256][8];
    __shared__ float red[256][9];
    __shared__ float zn2[8];
    __shared__ float rd[256];
    __shared__ int   ri[256];
    __shared__ int   bestsh[8];

#pragma unroll
    for (int rr = 0; rr < 8; ++rr) {
        int r = r0 + rr, b = r >> 6, s = r & 63;
        zT[tid][rr] = z[((size_t)(b * 256 + tid)) * 64 + s];
    }
    __syncthreads();
#pragma unroll
    for (int rr = 0; rr < 8; ++rr) { float v = zT[tid][rr]; red[tid][rr] = v * v; }
    __syncthreads();
    for (int off = 128; off > 0; off >>= 1) {
        if (tid < off) {
#pragma unroll
            for (int rr = 0; rr < 8; ++rr) red[tid][rr] += red[tid + off][rr];
        }
        __syncthreads();
    }
    if (tid < 8) zn2[tid] = red[0][tid];
    __syncthreads();

    float d0[8], d1[8];
#pragma unroll
    for (int rr = 0; rr < 8; ++rr) { d0[rr] = 0.f; d1[rr] = 0.f; }
    float cn0 = 0.f, cn1 = 0.f;

    for (int c = 0; c < 256; ++c) {
        float cv0 = cbT[c * 512 + tid];
        float cv1 = cbT[c * 512 + 256 + tid];
        cn0 += cv0 * cv0;
        cn1 += cv1 * cv1;
        float4 za = *(const float4*)&zT[c][0];
        float4 zb = *(const float4*)&zT[c][4];
        const float* zv = (const float*)&za;
        const float* zw = (const float*)&zb;
#pragma unroll
        for (int rr = 0; rr < 4; ++rr) {
            d0[rr]     += zv[rr] * cv0;  d1[rr]     += zv[rr] * cv1;
            d0[rr + 4] += zw[rr] * cv0;  d1[rr + 4] += zw[rr] * cv1;
        }
    }

#pragma unroll
    for (int rr = 0; rr < 8; ++rr) {
        float dist0 = zn2[rr] - 2.f * d0[rr] + cn0;
        float dist1 = zn2[rr] - 2.f * d1[rr] + cn1;
        float bd = dist0; int bi = tid;
        if (dist1 < bd) { bd = dist1; bi = tid + 256; }
        rd[tid] = bd; ri[tid] = bi;
        __syncthreads();
        for (int off = 128; off > 0; off >>= 1) {
            if (tid < off) {
                float od = rd[tid + off]; int oi = ri[tid + off];
                if (od < rd[tid] || (od == rd[tid] && oi < ri[tid])) { rd[tid] = od; ri[tid] = oi; }
            }
            __syncthreads();
        }
        if (tid == 0) {
            int r = r0 + rr;
            bestsh[rr] = ri[0];
            dout[OUT_IDX + r]  = (float)ri[0];
            dout[OUT_MIND + r] = rd[0];
        }
        __syncthreads();
    }

#pragma unroll
    for (int rr = 0; rr < 8; ++rr) {
        int r = r0 + rr, b = r >> 6, s = r & 63;
        q[((size_t)(b * 256 + tid)) * 64 + s] = cb[(size_t)bestsh[rr] * 256 + tid];
    }
}

__global__ void vq_loss(float* __restrict__ dout) {
    int tid = threadIdx.x;
    __shared__ float red[256];
    float s = 0.f;
    for (int i = tid; i < 1024; i += 256) s += dout[OUT_MIND + i];
    red[tid] = s;
    __syncthreads();
    for (int off = 128; off > 0; off >>= 1) {
        if (tid < off) red[tid] += red[tid + off];
        __syncthreads();
    }
    if (tid == 0) {
        float loss = red[0] / 262144.f;
        dout[OUT_CL] = loss;
        dout[OUT_CB] = loss;
    }
}

// ================= Final: BN(D2) + LeakyReLU + 1x1 conv (32->3) + tanh (verified) ==========
__global__ void final_conv_tanh(const float* __restrict__ hbuf, const float* __restrict__ bnt,
                                const float* __restrict__ g, const float* __restrict__ bt,
                                const float* __restrict__ w3, const float* __restrict__ b3,
                                float* __restrict__ out) {
    __shared__ float sc[32], sh[32];
    int tid = threadIdx.x;
    if (tid < 32) {
        float m = bnt[tid * 2] * (1.f / 262144.f);
        float var = bnt[tid * 2 + 1] * (1.f / 262144.f) - m * m;
        float scale = g[tid] * rsqrtf(var + 1e-5f);
        sc[tid] = scale;
        sh[tid] = bt[tid] - m * scale;
    }
    __syncthreads();
    int idx = blockIdx.x * 256 + tid;
    if (idx >= 16 * 16384) return;
    int hw = idx % 16384;
    int b  = idx / 16384;
    const float* hp = hbuf + ((size_t)b * 32) * 16384 + hw;
    float a0 = b3[0], a1 = b3[1], a2 = b3[2];
#pragma unroll
    for (int c = 0; c < 32; ++c) {
        float v = hp[(size_t)c * 16384];
        v = v * sc[c] + sh[c];
        v = v >= 0.f ? v : LEAK * v;
        a0 += v * w3[c];
        a1 += v * w3[32 + c];
        a2 += v * w3[64 + c];
    }
    size_t ob = ((size_t)b * 3) * 16384 + hw;
    out[ob]             = tanhf(a0);
    out[ob + 16384]     = tanhf(a1);
    out[ob + 2 * 16384] = tanhf(a2);
}

extern "C" void kernel_launch(void* const* d_in, const int* in_sizes, int n_in,
                              void* d_out, int out_size, void* d_ws, size_t ws_size,
                              hipStream_t stream) {
    const float* x      = (const float*)d_in[0];
    const float* enc_w0 = (const float*)d_in[1];
    const float* enc_b0 = (const float*)d_in[2];
    const float* enc_w1 = (const float*)d_in[3];
    const float* enc_b1 = (const float*)d_in[4];
    const float* enc_w2 = (const float*)d_in[5];
    const float* enc_b2 = (const float*)d_in[6];
    const float* enc_w3 = (const float*)d_in[7];
    const float* enc_b3 = (const float*)d_in[8];
    const float* ebn_g0 = (const float*)d_in[9];
    const float* ebn_b0 = (const float*)d_in[10];
    const float* ebn_g1 = (const float*)d_in[11];
    const float* ebn_b1 = (const float*)d_in[12];
    const float* ebn_g2 = (const float*)d_in[13];
    const float* ebn_b2 = (const float*)d_in[14];
    const float* cb     = (const float*)d_in[15];
    const float* dec_w0 = (const float*)d_in[16];
    const float* dec_b0 = (const float*)d_in[17];
    const float* dbn_g0 = (const float*)d_in[18];
    const float* dbn_b0 = (const float*)d_in[19];
    const float* dec_w1 = (const float*)d_in[20];
    const float* dec_b1 = (const float*)d_in[21];
    const float* dbn_g1 = (const float*)d_in[22];
    const float* dbn_b1 = (const float*)d_in[23];
    const float* dec_w2 = (const float*)d_in[24];
    const float* dec_b2 = (const float*)d_in[25];
    const float* dbn_g2 = (const float*)d_in[26];
    const float* dbn_b2 = (const float*)d_in[27];
    const float* dec_w3 = (const float*)d_in[28];
    const float* dec_b3 = (const float*)d_in[29];

    float* out = (float*)d_out;
    float* ws  = (float*)d_ws;

    // ---- workspace (float units); same layout as round 10 (verified) ----
    float*  Y0   = ws;                               // 4194304
    float*  Y1   = ws + 4194304;                     // 2097152
    float*  Y2   = ws + 6291456;                     // 1048576
    float*  Z    = ws + 7340032;                     // 262144
    float*  Q    = ws + 7602176;                     // 262144
    ushort* WH   = (ushort*)(ws + 7864320);          // 2269184 us
    ushort* WL   = (ushort*)(ws + 8998912);          // 2269184 us
    float*  CBT  = ws + 10133504;                    // 131072
    float*  BNT  = ws + 10264576;                    // 6144
    float*  PART = ws + 10270720;                    // 8388608
    float*  D0   = ws + 18659328;                    // 2097152
    float*  D1   = ws + 20756480;                    // 4194304
    float*  D2   = ws + 24950784;                    // 8388608

    dim3 blk(256);

    // ---- prologue (merged) ----
    prep_all<<<8864, blk, 0, stream>>>(enc_w1, enc_w2, enc_w3, dec_w0, dec_w1, dec_w2,
                                       WH, WL, cb, CBT, BNT);

    // ---- encoder ----
    conv4x4<8><<<2048, blk, 0, stream>>>(x, enc_w0, enc_b0, Y0, BNT, 16, 3, 128, 64, 64);

    // enc1: M=128 N=16384 K=1024, KS=4 -> 1024 blocks; B=Y0 raw + BN0
    gemm_mfma<0><<<1024, blk, 0, stream>>>(WH, WL, Y0,
        BNT, ebn_g0, ebn_b0, 1.f / 65536.f, 4, enc_b1, PART, nullptr,
        1, 256, 1024, 256, 4, 2097152, 64, 64, 128, 32, 5, 0, 0, 0, 0);
    reduce_bias_stats4<<<2048, blk, 0, stream>>>((const float4*)PART, enc_b1, (float4*)Y1,
                                                 BNT + 1024, 524288, 4, 128, 256, 1);

    // enc2: M=256 N=4096 K=2048, KS=8 -> 1024 blocks; B=Y1 raw + BN1
    gemm_mfma<0><<<1024, blk, 0, stream>>>(WH + 131072, WL + 131072, Y1,
        BNT + 1024, ebn_g1, ebn_b1, 1.f / 16384.f, 4, enc_b2, PART, nullptr,
        2, 64, 2048, 256, 8, 1048576, 128, 32, 256, 16, 4, 0, 0, 0, 0);
    reduce_bias_stats4<<<1024, blk, 0, stream>>>((const float4*)PART, enc_b2, (float4*)Y2,
                                                 BNT + 2048, 262144, 8, 256, 64, 4);

    // enc3: M=256 N=1024 K=4096, KS=32 -> 1024 blocks; B=Y2 raw + BN2
    gemm_mfma<0><<<1024, blk, 0, stream>>>(WH + 655360, WL + 655360, Y2,
        BNT + 2048, ebn_g2, ebn_b2, 1.f / 4096.f, 4, enc_b3, PART, nullptr,
        2, 16, 4096, 128, 32, 262144, 256, 16, 256, 8, 3, 0, 0, 0, 0);
    reduce_bias4<<<256, blk, 0, stream>>>((const float4*)PART, enc_b3, (float4*)Z, 65536, 32, 256, 16);

    // ---- vector quantizer ----
    vq_main<<<128, blk, 0, stream>>>(Z, CBT, cb, Q, out);
    vq_loss<<<1, blk, 0, stream>>>(out);

    // ---- decoder ----
    // dec0: M=2048 N=1024 K=256, KS=4 -> 1024 blocks; B=Q (no BN)
    gemm_mfma<1><<<1024, blk, 0, stream>>>(WH + 1703936, WL + 1703936, Q,
        nullptr, nullptr, nullptr, 0.f, 0, dec_b0, PART, nullptr,
        16, 16, 256, 64, 4, 2097152, 256, 8, 128, 0, 0, 6, 3, 7, 2);
    reduce_bias_stats4<<<2048, blk, 0, stream>>>((const float4*)PART, dec_b0, (float4*)D0,
                                                 BNT + 3072, 524288, 4, 128, 256, 1);

    // dec1: M=256 N=16384 K=128, KS=2 -> 1024 blocks; B=D0 raw + BN3
    gemm_mfma<1><<<1024, blk, 0, stream>>>(WH + 2228224, WL + 2228224, D0,
        BNT + 3072, dbn_g0, dbn_b0, 1.f / 16384.f, 0, dec_b1, PART, nullptr,
        2, 256, 128, 64, 2, 4194304, 128, 32, 64, 0, 0, 10, 5, 6, 1);
    reduce_bias_stats4<<<4096, blk, 0, stream>>>((const float4*)PART, dec_b1, (float4*)D1,
                                                 BNT + 4096, 1048576, 2, 64, 1024, 1);

    // dec2: M=128 N=65536 K=64, KS=1 -> 1024 blocks; B=D1 raw + BN4; direct write + fused stats
    gemm_mfma<1><<<1024, blk, 0, stream>>>(WH + 2260992, WL + 2260992, D1,
        BNT + 4096, dbn_g1, dbn_b1, 1.f / 65536.f, 0, dec_b2, D2, BNT + 5120,
        1, 1024, 64, 64, 1, 0, 64, 64, 32, 0, 0, 12, 6, 5, 1);

    // final: BN5 + leaky + 1x1 conv + tanh
    final_conv_tanh<<<1024, blk, 0, stream>>>(D2, BNT + 5120, dbn_g2, dbn_b2, dec_w3, dec_b3, out);
}

// Round 15
// 471.949 us; speedup vs baseline: 1.1670x; 1.0101x over previous
//
#include <hip/hip_runtime.h>
#include <math.h>

#define LEAK 0.01f

typedef __bf16 bf16x8 __attribute__((ext_vector_type(8)));
typedef float f32x4 __attribute__((ext_vector_type(4)));
typedef unsigned short ushort;
typedef unsigned int uint32;

struct HL { ushort h, l; };

// split fp32 into bf16 hi + bf16 lo (both RNE): x ~= hi + lo, err ~2^-17 rel
__device__ inline HL split_bf16(float x) {
    unsigned u = __float_as_uint(x);
    unsigned hr = (u + 0x7FFFu + ((u >> 16) & 1u)) >> 16;
    float fh = __uint_as_float(hr << 16);
    float r = x - fh;
    unsigned v = __float_as_uint(r);
    unsigned lr = (v + 0x7FFFu + ((v >> 16) & 1u)) >> 16;
    HL out; out.h = (ushort)hr; out.l = (ushort)lr;
    return out;
}

// ================= staged-B raw load: 64n x 32k fp32 tile, n-major lane map (r14) =========
template<int MODE>
__device__ inline void stage_load(float (&pv)[2][4], const float* __restrict__ Bf,
                                  int kbase, int n0, int tid,
                                  int Ci, int Hin, int Ho, int lgHo, int lgHW) {
#pragma unroll
    for (int r = 0; r < 2; ++r) {
        int g = r * 256 + tid;          // 0..511
        int nl = g & 63, kg = g >> 6;   // n-major: wave = one kg, 64 consecutive n
        int n = n0 + nl;
        if (MODE == 0) {
            int k4 = kbase + (kg << 2);
            int ic = k4 >> 4, kh = (k4 >> 2) & 3;
            int ow = n & (Ho - 1), oh = (n >> lgHo) & (Ho - 1), b = n >> (lgHo + lgHo);
            int ih = oh * 2 - 1 + kh;
            int ihc = ih < 0 ? 0 : (ih >= Hin ? Hin - 1 : ih);
            int iwb = ow * 2 - 1;
            size_t base = ((size_t)(b * Ci + ic) * Hin + ihc) * Hin;
#pragma unroll
            for (int e = 0; e < 4; ++e) {
                int iw = iwb + e;
                int iwc = iw < 0 ? 0 : (iw >= Hin ? Hin - 1 : iw);
                pv[r][e] = Bf[base + iwc];
            }
        } else {
            int c = kbase + (kg << 2);
            int b = n >> lgHW, hw = n & ((1 << lgHW) - 1);
            size_t base = (((size_t)(b * Ci + c)) << lgHW) + hw;
            size_t str = (size_t)1 << lgHW;
#pragma unroll
            for (int e = 0; e < 4; ++e) pv[r][e] = Bf[base + e * str];
        }
    }
}

// ================= bf16-split MFMA GEMM =================
// Block tile (64*MT)M x 64N, 4 waves of (16*MT)M x 64N each. K-step 32 (LDS stride 36).
// A: fragment-ordered bf16 hi/lo (r9).  B: raw fp32 + fused BN->leaky->mask->split->pack (r10).
// C = Ah*Bh + Ah*Bl + Al*Bh (r7).  Optional fused output BN-stats (Co<=128) for KS==1 MODE 1.
template<int MODE, int MT>
__global__ __launch_bounds__(256, 3) void gemm_mfma(
    const ushort* __restrict__ Ah, const ushort* __restrict__ Al,
    const float* __restrict__ Bf,
    const float* __restrict__ bnt, const float* __restrict__ gamma,
    const float* __restrict__ beta, float invN, int chanShift,
    const float* __restrict__ bias, float* __restrict__ P,
    float* __restrict__ statsOut,
    int Mtiles, int Ntiles, int K, int Kslice, int KS, int outSize,
    int Ci, int Hin, int Co, int Ho, int lgHo,
    int lgHW, int lgHin, int lgCo, int lgk)
{
    __shared__ __align__(16) uint32 Bsp[64 * 36];   // [n][k] packed, stride 36
    __shared__ float scs[256], shs[256];
    __shared__ float st1[128], st2[128];

    int bid = blockIdx.x;
    int ntile = bid % Ntiles; bid /= Ntiles;
    int mtile = bid % Mtiles;
    int ks = bid / Mtiles;
    int tid = threadIdx.x;
    int lane = tid & 63, w = tid >> 6;
    int quad = lane >> 4, tl = lane & 15;
    int n0 = ntile << 6, m0 = mtile * (MT << 6), k0 = ks * Kslice;
    int Kt = K >> 5;

    bool useBN = (bnt != nullptr);
    int c0 = k0 >> chanShift;
    if (useBN) {
        int nch = Kslice >> chanShift;
        for (int c = tid; c < nch; c += 256) {
            float m = bnt[(c0 + c) * 2] * invN;
            float var = bnt[(c0 + c) * 2 + 1] * invN - m * m;
            float scale = gamma[c0 + c] * rsqrtf(var + 1e-5f);
            scs[c] = scale;
            shs[c] = beta[c0 + c] - m * scale;
        }
    }
    if (MODE == 1 && statsOut && tid < 128) { st1[tid] = 0.f; st2[tid] = 0.f; }
    __syncthreads();

    f32x4 zero4 = {0.f, 0.f, 0.f, 0.f};
    f32x4 acc[MT][4];
#pragma unroll
    for (int mt = 0; mt < MT; ++mt)
#pragma unroll
        for (int nt = 0; nt < 4; ++nt) acc[mt][nt] = zero4;

    float pv[2][4];
    stage_load<MODE>(pv, Bf, k0, n0, tid, Ci, Hin, Ho, lgHo, lgHW);

    for (int kc = 0; kc < Kslice; kc += 32) {
        int kbase = k0 + kc;
        int kt = kbase >> 5;
        // ---- transform + regs -> LDS ----
#pragma unroll
        for (int r = 0; r < 2; ++r) {
            int g = r * 256 + tid;
            int nl = g & 63, kg = g >> 6;
            int k4 = kbase + (kg << 2);
            uint32 pk[4];
            if (MODE == 0) {
                int ic = k4 >> 4, kh = (k4 >> 2) & 3;
                int n = n0 + nl;
                int ow = n & (Ho - 1), oh = (n >> lgHo) & (Ho - 1);
                int ih = oh * 2 - 1 + kh;
                bool rowok = (unsigned)ih < (unsigned)Hin;
                int iwb = ow * 2 - 1;
                float sc_ = useBN ? scs[ic - c0] : 0.f;
                float sh_ = useBN ? shs[ic - c0] : 0.f;
#pragma unroll
                for (int e = 0; e < 4; ++e) {
                    int iw = iwb + e;
                    bool ok = rowok && ((unsigned)iw < (unsigned)Hin);
                    float f = pv[r][e];
                    if (useBN) { f = f * sc_ + sh_; f = f >= 0.f ? f : LEAK * f; }
                    if (!ok) f = 0.f;
                    HL s = split_bf16(f);
                    pk[e] = ((uint32)s.h << 16) | s.l;
                }
            } else {
#pragma unroll
                for (int e = 0; e < 4; ++e) {
                    float f = pv[r][e];
                    if (useBN) {
                        int lc = k4 + e - k0;
                        f = f * scs[lc] + shs[lc];
                        f = f >= 0.f ? f : LEAK * f;
                    }
                    HL s = split_bf16(f);
                    pk[e] = ((uint32)s.h << 16) | s.l;
                }
            }
            *(uint4*)&Bsp[nl * 36 + (kg << 2)] = make_uint4(pk[0], pk[1], pk[2], pk[3]);
        }
        __syncthreads();

        // ---- prefetch next B tile ----
        bool more = (kc + 32) < Kslice;
        float pvn[2][4];
        if (more) stage_load<MODE>(pvn, Bf, kbase + 32, n0, tid, Ci, Hin, Ho, lgHo, lgHW);

        // ---- A fragments: fragment-ordered global, coalesced 16B/lane ----
        bf16x8 afh[MT], afl[MT];
#pragma unroll
        for (int mt = 0; mt < MT; ++mt) {
            int mtAbs = (m0 >> 4) + w * MT + mt;
            size_t abase = (((size_t)mtAbs * Kt + kt) << 6) + lane;
            afh[mt] = *(const bf16x8*)(Ah + abase * 8);
            afl[mt] = *(const bf16x8*)(Al + abase * 8);
        }
        // ---- B fragments: LDS packed -> unpack via v_perm ----
        bf16x8 bfh[4], bfl[4];
#pragma unroll
        for (int nt = 0; nt < 4; ++nt) {
            int base = ((nt << 4) + tl) * 36 + (quad << 3);
            uint4 ua = *(const uint4*)&Bsp[base];
            uint4 ub = *(const uint4*)&Bsp[base + 4];
            union { uint32 u[4]; bf16x8 v; } H, L;
            H.u[0] = __builtin_amdgcn_perm(ua.y, ua.x, 0x07060302u);
            H.u[1] = __builtin_amdgcn_perm(ua.w, ua.z, 0x07060302u);
            H.u[2] = __builtin_amdgcn_perm(ub.y, ub.x, 0x07060302u);
            H.u[3] = __builtin_amdgcn_perm(ub.w, ub.z, 0x07060302u);
            L.u[0] = __builtin_amdgcn_perm(ua.y, ua.x, 0x05040100u);
            L.u[1] = __builtin_amdgcn_perm(ua.w, ua.z, 0x05040100u);
            L.u[2] = __builtin_amdgcn_perm(ub.y, ub.x, 0x05040100u);
            L.u[3] = __builtin_amdgcn_perm(ub.w, ub.z, 0x05040100u);
            bfh[nt] = H.v; bfl[nt] = L.v;
        }
        // ---- MFMAs ----
#pragma unroll
        for (int mt = 0; mt < MT; ++mt)
#pragma unroll
            for (int nt = 0; nt < 4; ++nt) {
                acc[mt][nt] = __builtin_amdgcn_mfma_f32_16x16x32_bf16(afh[mt], bfh[nt], acc[mt][nt], 0, 0, 0);
                acc[mt][nt] = __builtin_amdgcn_mfma_f32_16x16x32_bf16(afh[mt], bfl[nt], acc[mt][nt], 0, 0, 0);
                acc[mt][nt] = __builtin_amdgcn_mfma_f32_16x16x32_bf16(afl[mt], bfh[nt], acc[mt][nt], 0, 0, 0);
            }
        __syncthreads();
        if (more) {
#pragma unroll
            for (int r = 0; r < 2; ++r)
#pragma unroll
                for (int e = 0; e < 4; ++e) pv[r][e] = pvn[r][e];
        }
    }

    // ---- epilogue: D[m = quad*4+reg][n = tl] (verified r7-r14) ----
    float* dst = P + (size_t)ks * outSize;
    if (MODE == 0) {
#pragma unroll
        for (int nt = 0; nt < 4; ++nt) {
            int n = n0 + (nt << 4) + tl;
            int ow = n & (Ho - 1), oh = (n >> lgHo) & (Ho - 1), b = n >> (lgHo + lgHo);
#pragma unroll
            for (int mt = 0; mt < MT; ++mt) {
                int mb = m0 + w * (MT << 4) + (mt << 4) + (quad << 2);
#pragma unroll
                for (int r = 0; r < 4; ++r) {
                    int oc = mb + r;
                    float v = acc[mt][nt][r];
                    if (KS == 1) v += bias[oc];
                    dst[((size_t)(b * Co + oc) * Ho + oh) * Ho + ow] = v;
                }
            }
        }
    } else {
        int kf = 1 << lgk;
        int Ho2 = Hin << lgk;
        float s1p[4 * MT], s2p[4 * MT];
#pragma unroll
        for (int i = 0; i < 4 * MT; ++i) { s1p[i] = 0.f; s2p[i] = 0.f; }
#pragma unroll
        for (int nt = 0; nt < 4; ++nt) {
            int n = n0 + (nt << 4) + tl;
            int b = n >> lgHW, hw = n & ((1 << lgHW) - 1);
            int h = hw >> lgHin, wp = hw & (Hin - 1);
#pragma unroll
            for (int mt = 0; mt < MT; ++mt) {
                int mb = m0 + w * (MT << 4) + (mt << 4) + (quad << 2);
#pragma unroll
                for (int r = 0; r < 4; ++r) {
                    int m = mb + r;
                    int o = m & (Co - 1), ij = m >> lgCo;
                    int ii = ij >> lgk, jj = ij & (kf - 1);
                    float v = acc[mt][nt][r];
                    if (KS == 1) v += bias[o];
                    if (statsOut) { s1p[mt * 4 + r] += v; s2p[mt * 4 + r] += v * v; }
                    dst[((size_t)(b * Co + o) * Ho2 + (h << lgk) + ii) * Ho2 + (wp << lgk) + jj] = v;
                }
            }
        }
        if (statsOut) {
#pragma unroll
            for (int i = 0; i < 4 * MT; ++i) {
#pragma unroll
                for (int msk = 1; msk < 16; msk <<= 1) {
                    s1p[i] += __shfl_xor(s1p[i], msk);
                    s2p[i] += __shfl_xor(s2p[i], msk);
                }
            }
            if (tl == 0) {
#pragma unroll
                for (int i = 0; i < 4 * MT; ++i) {
                    int mt = i >> 2, r = i & 3;
                    int o = (m0 + w * (MT << 4) + (mt << 4) + (quad << 2) + r) & (Co - 1);
                    atomicAdd(&st1[o], s1p[i]);
                    atomicAdd(&st2[o], s2p[i]);
                }
            }
            __syncthreads();
            if (tid < Co) {
                atomicAdd(&statsOut[tid * 2],     st1[tid]);
                atomicAdd(&statsOut[tid * 2 + 1], st2[tid]);
            }
        }
    }
}

// ================= merged prologue (r11, verified) =================
__device__ inline int fragaddr(int m, int k, int K) {
    return ((((m >> 4) * (K >> 5) + (k >> 5)) << 9) | (((k >> 3) & 3) << 7) | ((m & 15) << 3) | (k & 7));
}

__global__ void prep_all(const float* __restrict__ w1, const float* __restrict__ w2,
                         const float* __restrict__ w3, const float* __restrict__ d0,
                         const float* __restrict__ d1, const float* __restrict__ d2,
                         ushort* __restrict__ WH, ushort* __restrict__ WL,
                         const float* __restrict__ cb, float* __restrict__ cbT,
                         float* __restrict__ bnt) {
    int idx = blockIdx.x * 256 + threadIdx.x;
    if (idx < 6144) bnt[idx] = 0.f;
    if (idx < 131072) {
        int k = idx & 511, c = idx >> 9;
        cbT[idx] = cb[k * 256 + c];
    }
    if (idx >= 2269184) return;
    float v; int dst;
    if (idx < 131072) {                      // enc1: M=128 K=1024
        int m = idx >> 10, k = idx & 1023;
        v = w1[idx];
        dst = fragaddr(m, k, 1024);
    } else if (idx < 655360) {               // enc2: M=256 K=2048
        int i = idx - 131072;
        int m = i >> 11, k = i & 2047;
        v = w2[i];
        dst = 131072 + fragaddr(m, k, 2048);
    } else if (idx < 1703936) {              // enc3: M=256 K=4096
        int i = idx - 655360;
        int m = i >> 12, k = i & 4095;
        v = w3[i];
        dst = 655360 + fragaddr(m, k, 4096);
    } else if (idx < 2228224) {              // dec0: M=2048 K=256
        int i = idx - 1703936;
        int m = i >> 8, c = i & 255;
        int o = m & 127, ij = m >> 7;
        v = d0[((size_t)c * 128 + o) * 16 + ij];
        dst = 1703936 + fragaddr(m, c, 256);
    } else if (idx < 2260992) {              // dec1: M=256 K=128
        int i = idx - 2228224;
        int m = i >> 7, c = i & 127;
        int o = m & 63, ij = m >> 6;
        v = d1[((size_t)c * 64 + o) * 4 + ij];
        dst = 2228224 + fragaddr(m, c, 128);
    } else {                                 // dec2: M=128 K=64
        int i = idx - 2260992;
        int m = i >> 6, c = i & 63;
        int o = m & 31, ij = m >> 5;
        v = d2[((size_t)c * 32 + o) * 4 + ij];
        dst = 2260992 + fragaddr(m, c, 64);
    }
    HL s = split_bf16(v);
    WH[dst] = s.h; WL[dst] = s.l;
}

// ================= enc0 direct conv (Ci=3) with fused BN stats (r11, verified) =================
template<int OCT>
__global__ __launch_bounds__(256) void conv4x4(
    const float* __restrict__ x, const float* __restrict__ w,
    const float* __restrict__ bias, float* __restrict__ P,
    float* __restrict__ bnt,
    int B, int Ci, int Hin, int Co, int Ho)
{
    int ogn = Co / OCT;
    int ntile = (B * Ho * Ho) >> 8;
    int bid = blockIdx.x;
    int tile = bid % ntile; bid /= ntile;
    int og = bid % ogn;
    int oc0 = og * OCT;

    int px = (tile << 8) + threadIdx.x;
    int ow = px % Ho; int t = px / Ho;
    int oh = t % Ho;  int b = t / Ho;

    int off[16]; float fm[16];
    int ih0 = oh * 2 - 1, iw0 = ow * 2 - 1;
#pragma unroll
    for (int kh = 0; kh < 4; ++kh)
#pragma unroll
        for (int kw = 0; kw < 4; ++kw) {
            int ih = ih0 + kh, iw = iw0 + kw;
            bool ok = (ih >= 0) && (ih < Hin) && (iw >= 0) && (iw < Hin);
            int ihc = ih < 0 ? 0 : (ih >= Hin ? Hin - 1 : ih);
            int iwc = iw < 0 ? 0 : (iw >= Hin ? Hin - 1 : iw);
            off[kh * 4 + kw] = ihc * Hin + iwc;
            fm[kh * 4 + kw] = ok ? 1.f : 0.f;
        }

    float acc[OCT];
#pragma unroll
    for (int u = 0; u < OCT; ++u) acc[u] = bias[oc0 + u];

    const float* xc = x + (size_t)b * Ci * Hin * Hin;
    const float* wi = w + (size_t)oc0 * Ci * 16;
    int HinHin = Hin * Hin;
    for (int ic = 0; ic < Ci; ++ic) {
        float xv[16];
#pragma unroll
        for (int q = 0; q < 16; ++q) xv[q] = xc[off[q]] * fm[q];
#pragma unroll
        for (int u = 0; u < OCT; ++u) {
            const float* wo = wi + (size_t)u * Ci * 16;
            float a = acc[u];
#pragma unroll
            for (int q = 0; q < 16; ++q) a += xv[q] * wo[q];
            acc[u] = a;
        }
        xc += HinHin;
        wi += 16;
    }
    size_t obase = (((size_t)b * Co + oc0) * Ho + oh) * Ho + ow;
    size_t opl = (size_t)Ho * Ho;
#pragma unroll
    for (int u = 0; u < OCT; ++u) P[obase + u * opl] = acc[u];

    __shared__ float sm[OCT], sq[OCT];
    if (threadIdx.x < OCT) { sm[threadIdx.x] = 0.f; sq[threadIdx.x] = 0.f; }
    __syncthreads();
#pragma unroll
    for (int u = 0; u < OCT; ++u) {
        float a = acc[u], b2 = acc[u] * acc[u];
#pragma unroll
        for (int o2 = 32; o2 > 0; o2 >>= 1) {
            a += __shfl_down(a, o2);
            b2 += __shfl_down(b2, o2);
        }
        if ((threadIdx.x & 63) == 0) { atomicAdd(&sm[u], a); atomicAdd(&sq[u], b2); }
    }
    __syncthreads();
    if (threadIdx.x < OCT) {
        atomicAdd(&bnt[(oc0 + threadIdx.x) * 2],     sm[threadIdx.x]);
        atomicAdd(&bnt[(oc0 + threadIdx.x) * 2 + 1], sq[threadIdx.x]);
    }
}

// ================= reduce partials / BN stats (verified; encoder only now) =================
__global__ void reduce_bias4(const float4* __restrict__ P, const float* __restrict__ bias,
                             float4* __restrict__ y, int outSize4, int KS, int Co, int HW4) {
    int i = blockIdx.x * 256 + threadIdx.x;
    if (i >= outSize4) return;
    float bv = bias[(i / HW4) % Co];
    float4 s = make_float4(bv, bv, bv, bv);
    for (int ks = 0; ks < KS; ++ks) {
        float4 p = P[(size_t)ks * outSize4 + i];
        s.x += p.x; s.y += p.y; s.z += p.z; s.w += p.w;
    }
    y[i] = s;
}

__global__ void reduce_bias_stats4(const float4* __restrict__ P, const float* __restrict__ bias,
                                   float4* __restrict__ y, float* __restrict__ bnt,
                                   int outSize4, int KS, int Co, int HW4, int nch) {
    int tid = threadIdx.x;
    int i = blockIdx.x * 256 + tid;
    int c = (i / HW4) % Co;
    float bv = bias[c];
    float4 s = make_float4(bv, bv, bv, bv);
    for (int ks = 0; ks < KS; ++ks) {
        float4 p = P[(size_t)ks * outSize4 + i];
        s.x += p.x; s.y += p.y; s.z += p.z; s.w += p.w;
    }
    y[i] = s;
    float ls  = s.x + s.y + s.z + s.w;
    float ls2 = s.x * s.x + s.y * s.y + s.z * s.z + s.w * s.w;
    __shared__ float as[16], aq[16];
    if (tid < 16) { as[tid] = 0.f; aq[tid] = 0.f; }
    __syncthreads();
    int c0 = ((blockIdx.x * 256) / HW4) % Co;
    atomicAdd(&as[c - c0], ls);
    atomicAdd(&aq[c - c0], ls2);
    __syncthreads();
    if (tid < nch) {
        atomicAdd(&bnt[(c0 + tid) * 2],     as[tid]);
        atomicAdd(&bnt[(c0 + tid) * 2 + 1], aq[tid]);
    }
}

// ================= Vector quantizer (verified) =================
#define OUT_CL   786432
#define OUT_CB   786433
#define OUT_IDX  786434
#define OUT_MIND 787458

__global__ void vq_main(const float* __restrict__ z, const float* __restrict__ cbT,
                        const float* __restrict__ cb,
                        float* __restrict__ q, float* __restrict__ dout) {
    int r0 = blockIdx.x * 8;
    int tid = threadIdx.x;

    __shared__ float zT[256][8];
    __shared__ float red[256][9];
    __shared__ float zn2[8];
    __shared__ float rd[256];
    __shared__ int   ri[256];
    __shared__ int   bestsh[8];

#pragma unroll
    for (int rr = 0; rr < 8; ++rr) {
        int r = r0 + rr, b = r >> 6, s = r & 63;
        zT[tid][rr] = z[((size_t)(b * 256 + tid)) * 64 + s];
    }
    __syncthreads();
#pragma unroll
    for (int rr = 0; rr < 8; ++rr) { float v = zT[tid][rr]; red[tid][rr] = v * v; }
    __syncthreads();
    for (int off = 128; off > 0; off >>= 1) {
        if (tid < off) {
#pragma unroll
            for (int rr = 0; rr < 8; ++rr) red[tid][rr] += red[tid + off][rr];
        }
        __syncthreads();
    }
    if (tid < 8) zn2[tid] = red[0][tid];
    __syncthreads();

    float d0[8], d1[8];
#pragma unroll
    for (int rr = 0; rr < 8; ++rr) { d0[rr] = 0.f; d1[rr] = 0.f; }
    float cn0 = 0.f, cn1 = 0.f;

    for (int c = 0; c < 256; ++c) {
        float cv0 = cbT[c * 512 + tid];
        float cv1 = cbT[c * 512 + 256 + tid];
        cn0 += cv0 * cv0;
        cn1 += cv1 * cv1;
        float4 za = *(const float4*)&zT[c][0];
        float4 zb = *(const float4*)&zT[c][4];
        const float* zv = (const float*)&za;
        const float* zw = (const float*)&zb;
#pragma unroll
        for (int rr = 0; rr < 4; ++rr) {
            d0[rr]     += zv[rr] * cv0;  d1[rr]     += zv[rr] * cv1;
            d0[rr + 4] += zw[rr] * cv0;  d1[rr + 4] += zw[rr] * cv1;
        }
    }

#pragma unroll
    for (int rr = 0; rr < 8; ++rr) {
        float dist0 = zn2[rr] - 2.f * d0[rr] + cn0;
        float dist1 = zn2[rr] - 2.f * d1[rr] + cn1;
        float bd = dist0; int bi = tid;
        if (dist1 < bd) { bd = dist1; bi = tid + 256; }
        rd[tid] = bd; ri[tid] = bi;
        __syncthreads();
        for (int off = 128; off > 0; off >>= 1) {
            if (tid < off) {
                float od = rd[tid + off]; int oi = ri[tid + off];
                if (od < rd[tid] || (od == rd[tid] && oi < ri[tid])) { rd[tid] = od; ri[tid] = oi; }
            }
            __syncthreads();
        }
        if (tid == 0) {
            int r = r0 + rr;
            bestsh[rr] = ri[0];
            dout[OUT_IDX + r]  = (float)ri[0];
            dout[OUT_MIND + r] = rd[0];
        }
        __syncthreads();
    }

#pragma unroll
    for (int rr = 0; rr < 8; ++rr) {
        int r = r0 + rr, b = r >> 6, s = r & 63;
        q[((size_t)(b * 256 + tid)) * 64 + s] = cb[(size_t)bestsh[rr] * 256 + tid];
    }
}

__global__ void vq_loss(float* __restrict__ dout) {
    int tid = threadIdx.x;
    __shared__ float red[256];
    float s = 0.f;
    for (int i = tid; i < 1024; i += 256) s += dout[OUT_MIND + i];
    red[tid] = s;
    __syncthreads();
    for (int off = 128; off > 0; off >>= 1) {
        if (tid < off) red[tid] += red[tid + off];
        __syncthreads();
    }
    if (tid == 0) {
        float loss = red[0] / 262144.f;
        dout[OUT_CL] = loss;
        dout[OUT_CB] = loss;
    }
}

// ================= Final: BN(D2) + LeakyReLU + 1x1 conv (32->3) + tanh (verified) ==========
__global__ void final_conv_tanh(const float* __restrict__ hbuf, const float* __restrict__ bnt,
                                const float* __restrict__ g, const float* __restrict__ bt,
                                const float* __restrict__ w3, const float* __restrict__ b3,
                                float* __restrict__ out) {
    __shared__ float sc[32], sh[32];
    int tid = threadIdx.x;
    if (tid < 32) {
        float m = bnt[tid * 2] * (1.f / 262144.f);
        float var = bnt[tid * 2 + 1] * (1.f / 262144.f) - m * m;
        float scale = g[tid] * rsqrtf(var + 1e-5f);
        sc[tid] = scale;
        sh[tid] = bt[tid] - m * scale;
    }
    __syncthreads();
    int idx = blockIdx.x * 256 + tid;
    if (idx >= 16 * 16384) return;
    int hw = idx % 16384;
    int b  = idx / 16384;
    const float* hp = hbuf + ((size_t)b * 32) * 16384 + hw;
    float a0 = b3[0], a1 = b3[1], a2 = b3[2];
#pragma unroll
    for (int c = 0; c < 32; ++c) {
        float v = hp[(size_t)c * 16384];
        v = v * sc[c] + sh[c];
        v = v >= 0.f ? v : LEAK * v;
        a0 += v * w3[c];
        a1 += v * w3[32 + c];
        a2 += v * w3[64 + c];
    }
    size_t ob = ((size_t)b * 3) * 16384 + hw;
    out[ob]             = tanhf(a0);
    out[ob + 16384]     = tanhf(a1);
    out[ob + 2 * 16384] = tanhf(a2);
}

extern "C" void kernel_launch(void* const* d_in, const int* in_sizes, int n_in,
                              void* d_out, int out_size, void* d_ws, size_t ws_size,
                              hipStream_t stream) {
    const float* x      = (const float*)d_in[0];
    const float* enc_w0 = (const float*)d_in[1];
    const float* enc_b0 = (const float*)d_in[2];
    const float* enc_w1 = (const float*)d_in[3];
    const float* enc_b1 = (const float*)d_in[4];
    const float* enc_w2 = (const float*)d_in[5];
    const float* enc_b2 = (const float*)d_in[6];
    const float* enc_w3 = (const float*)d_in[7];
    const float* enc_b3 = (const float*)d_in[8];
    const float* ebn_g0 = (const float*)d_in[9];
    const float* ebn_b0 = (const float*)d_in[10];
    const float* ebn_g1 = (const float*)d_in[11];
    const float* ebn_b1 = (const float*)d_in[12];
    const float* ebn_g2 = (const float*)d_in[13];
    const float* ebn_b2 = (const float*)d_in[14];
    const float* cb     = (const float*)d_in[15];
    const float* dec_w0 = (const float*)d_in[16];
    const float* dec_b0 = (const float*)d_in[17];
    const float* dbn_g0 = (const float*)d_in[18];
    const float* dbn_b0 = (const float*)d_in[19];
    const float* dec_w1 = (const float*)d_in[20];
    const float* dec_b1 = (const float*)d_in[21];
    const float* dbn_g1 = (const float*)d_in[22];
    const float* dbn_b1 = (const float*)d_in[23];
    const float* dec_w2 = (const float*)d_in[24];
    const float* dec_b2 = (const float*)d_in[25];
    const float* dbn_g2 = (const float*)d_in[26];
    const float* dbn_b2 = (const float*)d_in[27];
    const float* dec_w3 = (const float*)d_in[28];
    const float* dec_b3 = (const float*)d_in[29];

    float* out = (float*)d_out;
    float* ws  = (float*)d_ws;

    // ---- workspace (float units); same layout as round 10 (verified) ----
    float*  Y0   = ws;                               // 4194304
    float*  Y1   = ws + 4194304;                     // 2097152
    float*  Y2   = ws + 6291456;                     // 1048576
    float*  Z    = ws + 7340032;                     // 262144
    float*  Q    = ws + 7602176;                     // 262144
    ushort* WH   = (ushort*)(ws + 7864320);          // 2269184 us
    ushort* WL   = (ushort*)(ws + 8998912);          // 2269184 us
    float*  CBT  = ws + 10133504;                    // 131072
    float*  BNT  = ws + 10264576;                    // 6144
    float*  PART = ws + 10270720;                    // 8388608
    float*  D0   = ws + 18659328;                    // 2097152
    float*  D1   = ws + 20756480;                    // 4194304
    float*  D2   = ws + 24950784;                    // 8388608

    dim3 blk(256);

    // ---- prologue (merged) ----
    prep_all<<<8864, blk, 0, stream>>>(enc_w1, enc_w2, enc_w3, dec_w0, dec_w1, dec_w2,
                                       WH, WL, cb, CBT, BNT);

    // ---- encoder ----
    conv4x4<8><<<2048, blk, 0, stream>>>(x, enc_w0, enc_b0, Y0, BNT, 16, 3, 128, 64, 64);

    // enc1: M=128 N=16384 K=1024, KS=4 -> 1024 blocks; B=Y0 raw + BN0
    gemm_mfma<0, 2><<<1024, blk, 0, stream>>>(WH, WL, Y0,
        BNT, ebn_g0, ebn_b0, 1.f / 65536.f, 4, enc_b1, PART, nullptr,
        1, 256, 1024, 256, 4, 2097152, 64, 64, 128, 32, 5, 0, 0, 0, 0);
    reduce_bias_stats4<<<2048, blk, 0, stream>>>((const float4*)PART, enc_b1, (float4*)Y1,
                                                 BNT + 1024, 524288, 4, 128, 256, 1);

    // enc2: M=256 N=4096 K=2048, KS=8 -> 1024 blocks; B=Y1 raw + BN1
    gemm_mfma<0, 2><<<1024, blk, 0, stream>>>(WH + 131072, WL + 131072, Y1,
        BNT + 1024, ebn_g1, ebn_b1, 1.f / 16384.f, 4, enc_b2, PART, nullptr,
        2, 64, 2048, 256, 8, 1048576, 128, 32, 256, 16, 4, 0, 0, 0, 0);
    reduce_bias_stats4<<<1024, blk, 0, stream>>>((const float4*)PART, enc_b2, (float4*)Y2,
                                                 BNT + 2048, 262144, 8, 256, 64, 4);

    // enc3: M=256 N=1024 K=4096, KS=32 -> 1024 blocks; B=Y2 raw + BN2
    gemm_mfma<0, 2><<<1024, blk, 0, stream>>>(WH + 655360, WL + 655360, Y2,
        BNT + 2048, ebn_g2, ebn_b2, 1.f / 4096.f, 4, enc_b3, PART, nullptr,
        2, 16, 4096, 128, 32, 262144, 256, 16, 256, 8, 3, 0, 0, 0, 0);
    reduce_bias4<<<256, blk, 0, stream>>>((const float4*)PART, enc_b3, (float4*)Z, 65536, 32, 256, 16);

    // ---- vector quantizer ----
    vq_main<<<128, blk, 0, stream>>>(Z, CBT, cb, Q, out);
    vq_loss<<<1, blk, 0, stream>>>(out);

    // ---- decoder (all KS=1, direct write + bias + fused stats) ----
    // dec0: MT=1 block 64x64, Mtiles=32 x Ntiles=16 = 512 blocks, K=256 (8 iters); B=Q (no BN)
    gemm_mfma<1, 1><<<512, blk, 0, stream>>>(WH + 1703936, WL + 1703936, Q,
        nullptr, nullptr, nullptr, 0.f, 0, dec_b0, D0, BNT + 3072,
        32, 16, 256, 256, 1, 0, 256, 8, 128, 0, 0, 6, 3, 7, 2);

    // dec1: MT=2, Mtiles=2 x Ntiles=256 = 512 blocks, K=128 (4 iters); B=D0 raw + BN3
    gemm_mfma<1, 2><<<512, blk, 0, stream>>>(WH + 2228224, WL + 2228224, D0,
        BNT + 3072, dbn_g0, dbn_b0, 1.f / 16384.f, 0, dec_b1, D1, BNT + 4096,
        2, 256, 128, 128, 1, 0, 128, 32, 64, 0, 0, 10, 5, 6, 1);

    // dec2: MT=2, Mtiles=1 x Ntiles=1024 = 1024 blocks, K=64; B=D1 raw + BN4
    gemm_mfma<1, 2><<<1024, blk, 0, stream>>>(WH + 2260992, WL + 2260992, D1,
        BNT + 4096, dbn_g1, dbn_b1, 1.f / 65536.f, 0, dec_b2, D2, BNT + 5120,
        1, 1024, 64, 64, 1, 0, 64, 64, 32, 0, 0, 12, 6, 5, 1);

    // final: BN5 + leaky + 1x1 conv + tanh
    final_conv_tanh<<<1024, blk, 0, stream>>>(D2, BNT + 5120, dbn_g2, dbn_b2, dec_w3, dec_b3, out);
}